// Round 1
// baseline (1312.911 us; speedup 1.0000x reference)
//
#include <hip/hip_runtime.h>

#define NNODES 50000
#define NFEAT 256
#define NHID 32
#define NHEADS 8
#define NCLASSES 32
#define NEDGES 800000
#define ETOT (NEDGES + NNODES)   // 850000 with self loops
#define HC 256                    // NHEADS*NHID

__device__ __forceinline__ unsigned enc_f(float f) {
    unsigned u = __float_as_uint(f);
    return (u & 0x80000000u) ? ~u : (u | 0x80000000u);
}
__device__ __forceinline__ float dec_f(unsigned u) {
    return (u & 0x80000000u) ? __uint_as_float(u ^ 0x80000000u)
                             : __uint_as_float(~u);
}
__device__ __forceinline__ void get_edge(const int* __restrict__ ei, int e,
                                         int& s, int& d) {
    if (e < NEDGES) { s = ei[e]; d = ei[NEDGES + e]; }
    else            { s = e - NEDGES; d = s; }
}
__device__ __forceinline__ float lrelu(float x) { return x > 0.f ? x : 0.2f * x; }

// ---------- GEMM1: z1[N,256] = x[N,256] @ W1[256,256] + b1 ----------
#define NPB 4
__global__ void gemm1_k(const float* __restrict__ x, const float* __restrict__ W,
                        const float* __restrict__ b, float* __restrict__ z) {
    __shared__ float xs[NPB][256];
    int n0 = blockIdx.x * NPB;
    int t = threadIdx.x;
#pragma unroll
    for (int i = 0; i < NPB; ++i) {
        int n = n0 + i;
        xs[i][t] = (n < NNODES) ? x[n * 256 + t] : 0.f;
    }
    __syncthreads();
    float acc[NPB] = {0.f, 0.f, 0.f, 0.f};
    for (int k = 0; k < 256; ++k) {
        float w = W[k * 256 + t];
#pragma unroll
        for (int i = 0; i < NPB; ++i) acc[i] += xs[i][k] * w;
    }
    float bb = b[t];
#pragma unroll
    for (int i = 0; i < NPB; ++i) {
        int n = n0 + i;
        if (n < NNODES) z[n * 256 + t] = acc[i] + bb;
    }
}

// ---------- GEMM2: z2[N,32] = h1[N,256] @ W2[256,32] + b2... (no bias here; bias b2 added at end) ----------
__global__ void gemm2_k(const float* __restrict__ h, const float* __restrict__ W,
                        float* __restrict__ z) {
    __shared__ float hs[8][256];
    int n0 = blockIdx.x * 8;
    int t = threadIdx.x;
#pragma unroll
    for (int i = 0; i < 8; ++i) {
        int n = n0 + i;
        hs[i][t] = (n < NNODES) ? h[n * 256 + t] : 0.f;
    }
    __syncthreads();
    int r = t >> 5, c = t & 31;
    float acc = 0.f;
    for (int k = 0; k < 256; ++k) acc += hs[r][k] * W[k * 32 + c];
    int n = n0 + r;
    if (n < NNODES) z[n * 32 + c] = acc;
}

// ---------- attention coefficients layer 1: per (node, head) ----------
__global__ void attn1_k(const float* __restrict__ z, const float* __restrict__ av,
                        const float* __restrict__ bv, float* __restrict__ as_,
                        float* __restrict__ ad_) {
    int id = blockIdx.x * blockDim.x + threadIdx.x;
    if (id >= NNODES * NHEADS) return;
    int n = id >> 3, h = id & 7;
    const float* zp = z + n * 256 + h * 32;
    const float* ap = av + h * 32;
    const float* bp = bv + h * 32;
    float s = 0.f, d = 0.f;
#pragma unroll
    for (int c = 0; c < 32; ++c) { float v = zp[c]; s += v * ap[c]; d += v * bp[c]; }
    as_[id] = s;
    ad_[id] = d;
}

// ---------- attention coefficients layer 2: per node ----------
__global__ void attn2_k(const float* __restrict__ z, const float* __restrict__ av,
                        const float* __restrict__ bv, float* __restrict__ as_,
                        float* __restrict__ ad_) {
    int n = blockIdx.x * blockDim.x + threadIdx.x;
    if (n >= NNODES) return;
    float s = 0.f, d = 0.f;
#pragma unroll
    for (int c = 0; c < 32; ++c) { float v = z[n * 32 + c]; s += v * av[c]; d += v * bv[c]; }
    as_[n] = s;
    ad_[n] = d;
}

// ---------- segment max over incoming edges ----------
template <int H>
__global__ void edge_max_k(const int* __restrict__ ei, const float* __restrict__ as_,
                           const float* __restrict__ ad_, unsigned* __restrict__ m) {
    int id = blockIdx.x * blockDim.x + threadIdx.x;
    if (id >= ETOT * H) return;
    int e = id / H, h = id % H;
    int s, d;
    get_edge(ei, e, s, d);
    float l = lrelu(as_[s * H + h] + ad_[d * H + h]);
    atomicMax(&m[d * H + h], enc_f(l));
}

// ---------- segment sum of exp(logit - max) ----------
template <int H>
__global__ void edge_denom_k(const int* __restrict__ ei, const float* __restrict__ as_,
                             const float* __restrict__ ad_, const unsigned* __restrict__ m,
                             float* __restrict__ dn) {
    int id = blockIdx.x * blockDim.x + threadIdx.x;
    if (id >= ETOT * H) return;
    int e = id / H, h = id % H;
    int s, d;
    get_edge(ei, e, s, d);
    float l = lrelu(as_[s * H + h] + ad_[d * H + h]);
    float w = expf(l - dec_f(m[d * H + h]));
    atomicAdd(&dn[d * H + h], w);
}

// ---------- aggregate layer 1: one block per edge, 256 threads = (h,c) ----------
__global__ void edge_agg1_k(const int* __restrict__ ei, const float* __restrict__ z,
                            const float* __restrict__ as_, const float* __restrict__ ad_,
                            const unsigned* __restrict__ m, const float* __restrict__ dn,
                            float* __restrict__ agg) {
    int e = blockIdx.x;
    int t = threadIdx.x;
    int h = t >> 5;
    int s, d;
    get_edge(ei, e, s, d);
    float l = lrelu(as_[s * 8 + h] + ad_[d * 8 + h]);
    float alpha = expf(l - dec_f(m[d * 8 + h])) / dn[d * 8 + h];
    atomicAdd(&agg[d * 256 + t], z[s * 256 + t] * alpha);
}

// ---------- aggregate layer 2: thread per (edge, class) ----------
__global__ void edge_agg2_k(const int* __restrict__ ei, const float* __restrict__ z,
                            const float* __restrict__ as_, const float* __restrict__ ad_,
                            const unsigned* __restrict__ m, const float* __restrict__ dn,
                            float* __restrict__ out) {
    int id = blockIdx.x * blockDim.x + threadIdx.x;
    if (id >= ETOT * 32) return;
    int e = id >> 5, c = id & 31;
    int s, d;
    get_edge(ei, e, s, d);
    float l = lrelu(as_[s] + ad_[d]);
    float alpha = expf(l - dec_f(m[d])) / dn[d];
    atomicAdd(&out[d * 32 + c], z[s * 32 + c] * alpha);
}

// ---------- ELU with bias (b1 is zeros but honor it) ----------
__global__ void elu_k(float* __restrict__ h, const float* __restrict__ b) {
    int id = blockIdx.x * blockDim.x + threadIdx.x;
    if (id >= NNODES * 256) return;
    float v = h[id] + b[id & 255];
    h[id] = v > 0.f ? v : expm1f(v);
}

// ---------- init out with broadcast b2 ----------
__global__ void init_out_k(float* __restrict__ out, const float* __restrict__ b) {
    int id = blockIdx.x * blockDim.x + threadIdx.x;
    if (id >= NNODES * 32) return;
    out[id] = b[id & 31];
}

extern "C" void kernel_launch(void* const* d_in, const int* in_sizes, int n_in,
                              void* d_out, int out_size, void* d_ws, size_t ws_size,
                              hipStream_t stream) {
    const float* x   = (const float*)d_in[0];
    const int*   ei  = (const int*)d_in[1];
    const float* W1  = (const float*)d_in[2];
    const float* av1 = (const float*)d_in[3];   // a_src1 [8,32]
    const float* bv1 = (const float*)d_in[4];   // a_dst1 [8,32]
    const float* b1  = (const float*)d_in[5];
    const float* W2  = (const float*)d_in[6];
    const float* av2 = (const float*)d_in[7];   // a_src2 [1,32]
    const float* bv2 = (const float*)d_in[8];   // a_dst2 [1,32]
    const float* b2  = (const float*)d_in[9];
    float* out = (float*)d_out;

    // workspace layout (floats)
    float*    z1 = (float*)d_ws;                  // 12,800,000
    float*    h1 = z1 + 12800000;                 // 12,800,000 (agg1 -> elu in place)
    float*    as1 = h1 + 12800000;                // 400,000
    float*    ad1 = as1 + 400000;                 // 400,000
    unsigned* m1  = (unsigned*)(ad1 + 400000);    // 400,000
    float*    dn1 = (float*)(m1 + 400000);        // 400,000
    float*    z2  = dn1 + 400000;                 // 1,600,000
    float*    as2 = z2 + 1600000;                 // 50,000
    float*    ad2 = as2 + 50000;                  // 50,000
    unsigned* m2  = (unsigned*)(ad2 + 50000);     // 50,000
    float*    dn2 = (float*)(m2 + 50000);         // 50,000

    // zero-init accumulators (m encodes: 0 < enc(any float), so 0 == -inf)
    hipMemsetAsync(h1, 0, (size_t)12800000 * 4, stream);
    hipMemsetAsync(m1, 0, (size_t)800000 * 4, stream);   // m1 + dn1 contiguous
    hipMemsetAsync(m2, 0, (size_t)100000 * 4, stream);   // m2 + dn2 contiguous

    // ---- layer 1 ----
    gemm1_k<<<(NNODES + NPB - 1) / NPB, 256, 0, stream>>>(x, W1, b1, z1);
    attn1_k<<<(NNODES * NHEADS + 255) / 256, 256, 0, stream>>>(z1, av1, bv1, as1, ad1);
    edge_max_k<8><<<(ETOT * 8 + 255) / 256, 256, 0, stream>>>(ei, as1, ad1, m1);
    edge_denom_k<8><<<(ETOT * 8 + 255) / 256, 256, 0, stream>>>(ei, as1, ad1, m1, dn1);
    edge_agg1_k<<<ETOT, 256, 0, stream>>>(ei, z1, as1, ad1, m1, dn1, h1);
    elu_k<<<(NNODES * 256 + 255) / 256, 256, 0, stream>>>(h1, b1);

    // ---- layer 2 ----
    gemm2_k<<<(NNODES + 7) / 8, 256, 0, stream>>>(h1, W2, z2);
    attn2_k<<<(NNODES + 255) / 256, 256, 0, stream>>>(z2, av2, bv2, as2, ad2);
    edge_max_k<1><<<(ETOT + 255) / 256, 256, 0, stream>>>(ei, as2, ad2, m2);
    edge_denom_k<1><<<(ETOT + 255) / 256, 256, 0, stream>>>(ei, as2, ad2, m2, dn2);
    init_out_k<<<(NNODES * 32 + 255) / 256, 256, 0, stream>>>(out, b2);
    edge_agg2_k<<<(ETOT * 32 + 255) / 256, 256, 0, stream>>>(ei, z2, as2, ad2, m2, dn2, out);
}

// Round 2
// 677.363 us; speedup vs baseline: 1.9383x; 1.9383x over previous
//
#include <hip/hip_runtime.h>

#define NNODES 50000
#define NFEAT 256
#define NHID 32
#define NHEADS 8
#define NCLASSES 32
#define NEDGES 800000
#define ETOT (NEDGES + NNODES)   // 850000 with self loops

__device__ __forceinline__ void get_edge(const int* __restrict__ ei, int e,
                                         int& s, int& d) {
    if (e < NEDGES) { s = ei[e]; d = ei[NEDGES + e]; }
    else            { s = e - NEDGES; d = s; }
}
__device__ __forceinline__ float lrelu(float x) { return x > 0.f ? x : 0.2f * x; }

// ---------- GEMM1: z1[N,256] = x[N,256] @ W1[256,256] + b1 ----------
#define NPB 4
__global__ void gemm1_k(const float* __restrict__ x, const float* __restrict__ W,
                        const float* __restrict__ b, float* __restrict__ z) {
    __shared__ float xs[NPB][256];
    int n0 = blockIdx.x * NPB;
    int t = threadIdx.x;
#pragma unroll
    for (int i = 0; i < NPB; ++i) {
        int n = n0 + i;
        xs[i][t] = (n < NNODES) ? x[n * 256 + t] : 0.f;
    }
    __syncthreads();
    float acc[NPB] = {0.f, 0.f, 0.f, 0.f};
    for (int k = 0; k < 256; ++k) {
        float w = W[k * 256 + t];
#pragma unroll
        for (int i = 0; i < NPB; ++i) acc[i] += xs[i][k] * w;
    }
    float bb = b[t];
#pragma unroll
    for (int i = 0; i < NPB; ++i) {
        int n = n0 + i;
        if (n < NNODES) z[n * 256 + t] = acc[i] + bb;
    }
}

// ---------- GEMM2: z2[N,32] = h1[N,256] @ W2[256,32] ----------
__global__ void gemm2_k(const float* __restrict__ h, const float* __restrict__ W,
                        float* __restrict__ z) {
    __shared__ float hs[8][256];
    int n0 = blockIdx.x * 8;
    int t = threadIdx.x;
#pragma unroll
    for (int i = 0; i < 8; ++i) {
        int n = n0 + i;
        hs[i][t] = (n < NNODES) ? h[n * 256 + t] : 0.f;
    }
    __syncthreads();
    int r = t >> 5, c = t & 31;
    float acc = 0.f;
    for (int k = 0; k < 256; ++k) acc += hs[r][k] * W[k * 32 + c];
    int n = n0 + r;
    if (n < NNODES) z[n * 32 + c] = acc;
}

// ---------- attention coefficients layer 1: per (node, head) ----------
__global__ void attn1_k(const float* __restrict__ z, const float* __restrict__ av,
                        const float* __restrict__ bv, float* __restrict__ as_,
                        float* __restrict__ ad_) {
    int id = blockIdx.x * blockDim.x + threadIdx.x;
    if (id >= NNODES * NHEADS) return;
    int n = id >> 3, h = id & 7;
    const float* zp = z + n * 256 + h * 32;
    const float* ap = av + h * 32;
    const float* bp = bv + h * 32;
    float s = 0.f, d = 0.f;
#pragma unroll
    for (int c = 0; c < 32; ++c) { float v = zp[c]; s += v * ap[c]; d += v * bp[c]; }
    as_[id] = s;
    ad_[id] = d;
}

// ---------- attention coefficients layer 2: per node ----------
__global__ void attn2_k(const float* __restrict__ z, const float* __restrict__ av,
                        const float* __restrict__ bv, float* __restrict__ as_,
                        float* __restrict__ ad_) {
    int n = blockIdx.x * blockDim.x + threadIdx.x;
    if (n >= NNODES) return;
    float s = 0.f, d = 0.f;
#pragma unroll
    for (int c = 0; c < 32; ++c) { float v = z[n * 32 + c]; s += v * av[c]; d += v * bv[c]; }
    as_[n] = s;
    ad_[n] = d;
}

// ---------- CSR build: histogram ----------
__global__ void hist_k(const int* __restrict__ ei, int* __restrict__ deg) {
    int e = blockIdx.x * blockDim.x + threadIdx.x;
    if (e >= ETOT) return;
    int s, d;
    get_edge(ei, e, s, d);
    atomicAdd(&deg[d], 1);
}

// ---------- CSR build: single-block exclusive scan over 50000 ints ----------
__global__ void scan_k(const int* __restrict__ deg, int* __restrict__ row_start) {
    __shared__ int ls[1024];
    __shared__ int carry_s;
    int t = threadIdx.x;
    if (t == 0) carry_s = 0;
    __syncthreads();
    for (int base = 0; base < NNODES; base += 1024) {
        int v = (base + t < NNODES) ? deg[base + t] : 0;
        ls[t] = v;
        __syncthreads();
        for (int off = 1; off < 1024; off <<= 1) {
            int x = (t >= off) ? ls[t - off] : 0;
            __syncthreads();
            ls[t] += x;
            __syncthreads();
        }
        int excl = carry_s + ls[t] - v;
        if (base + t < NNODES) row_start[base + t] = excl;
        __syncthreads();
        if (t == 1023) carry_s += ls[1023];
        __syncthreads();
    }
    if (t == 0) row_start[NNODES] = carry_s;
}

// ---------- CSR build: scatter src ids into dst buckets ----------
__global__ void scatter_k(const int* __restrict__ ei, const int* __restrict__ row_start,
                          int* __restrict__ cursor, int* __restrict__ csr_src) {
    int e = blockIdx.x * blockDim.x + threadIdx.x;
    if (e >= ETOT) return;
    int s, d;
    get_edge(ei, e, s, d);
    int pos = atomicAdd(&cursor[d], 1);
    csr_src[row_start[d] + pos] = s;
}

// ---------- fused layer-1 aggregation: online softmax + weighted sum + bias + ELU ----------
// one block (256 threads = 8 heads x 32 ch) per dst node
__global__ void agg1_csr_k(const int* __restrict__ row_start, const int* __restrict__ csr_src,
                           const float* __restrict__ z, const float* __restrict__ as_,
                           const float* __restrict__ ad_, const float* __restrict__ b,
                           float* __restrict__ h1) {
    int d = blockIdx.x;
    int t = threadIdx.x;
    int h = t >> 5;
    int beg = row_start[d], end = row_start[d + 1];
    float adh = ad_[d * 8 + h];
    float m = -1e30f, sum = 0.f, acc = 0.f;
    __shared__ int ss[64];
    for (int base = beg; base < end; base += 64) {
        int cnt = min(64, end - base);
        if (t < cnt) ss[t] = csr_src[base + t];
        __syncthreads();
        for (int i = 0; i < cnt; ++i) {
            int s = ss[i];
            float l = lrelu(as_[s * 8 + h] + adh);
            float zi = z[s * 256 + t];
            if (l > m) { float r = __expf(m - l); sum *= r; acc *= r; m = l; }
            float w = __expf(l - m);
            sum += w;
            acc += w * zi;
        }
        __syncthreads();
    }
    float v = acc / sum + b[t];
    h1[d * 256 + t] = v > 0.f ? v : expm1f(v);
}

// ---------- fused layer-2 aggregation + bias: 8 dst nodes per block, 32 lanes each ----------
__global__ void agg2_csr_k(const int* __restrict__ row_start, const int* __restrict__ csr_src,
                           const float* __restrict__ z2, const float* __restrict__ as_,
                           const float* __restrict__ ad_, const float* __restrict__ b,
                           float* __restrict__ out) {
    int g = blockIdx.x * 8 + (threadIdx.x >> 5);
    int c = threadIdx.x & 31;
    if (g >= NNODES) return;
    int beg = row_start[g], end = row_start[g + 1];
    float adn = ad_[g];
    float m = -1e30f, sum = 0.f, acc = 0.f;
    for (int i = beg; i < end; ++i) {
        int s = csr_src[i];
        float l = lrelu(as_[s] + adn);
        float zi = z2[s * 32 + c];
        if (l > m) { float r = __expf(m - l); sum *= r; acc *= r; m = l; }
        float w = __expf(l - m);
        sum += w;
        acc += w * zi;
    }
    out[g * 32 + c] = acc / sum + b[c];
}

extern "C" void kernel_launch(void* const* d_in, const int* in_sizes, int n_in,
                              void* d_out, int out_size, void* d_ws, size_t ws_size,
                              hipStream_t stream) {
    const float* x   = (const float*)d_in[0];
    const int*   ei  = (const int*)d_in[1];
    const float* W1  = (const float*)d_in[2];
    const float* av1 = (const float*)d_in[3];
    const float* bv1 = (const float*)d_in[4];
    const float* b1  = (const float*)d_in[5];
    const float* W2  = (const float*)d_in[6];
    const float* av2 = (const float*)d_in[7];
    const float* bv2 = (const float*)d_in[8];
    const float* b2  = (const float*)d_in[9];
    float* out = (float*)d_out;

    // workspace layout (4-byte elements)
    float* z1  = (float*)d_ws;             // 12,800,000
    float* h1  = z1 + 12800000;            // 12,800,000
    float* as1 = h1 + 12800000;            // 400,000
    float* ad1 = as1 + 400000;             // 400,000
    float* z2  = ad1 + 400000;             // 1,600,000
    float* as2 = z2 + 1600000;             // 50,000
    float* ad2 = as2 + 50000;              // 50,000
    int* deg       = (int*)(ad2 + 50000);  // 50,000
    int* cursor    = deg + 50000;          // 50,000   (contiguous w/ deg for one memset)
    int* row_start = cursor + 50000;       // 50,001
    int* csr_src   = row_start + 50001;    // 850,000

    hipMemsetAsync(deg, 0, (size_t)100000 * 4, stream);  // deg + cursor

    // ---- CSR build (shared by both layers) ----
    hist_k<<<(ETOT + 255) / 256, 256, 0, stream>>>(ei, deg);
    scan_k<<<1, 1024, 0, stream>>>(deg, row_start);
    scatter_k<<<(ETOT + 255) / 256, 256, 0, stream>>>(ei, row_start, cursor, csr_src);

    // ---- layer 1 ----
    gemm1_k<<<(NNODES + NPB - 1) / NPB, 256, 0, stream>>>(x, W1, b1, z1);
    attn1_k<<<(NNODES * NHEADS + 255) / 256, 256, 0, stream>>>(z1, av1, bv1, as1, ad1);
    agg1_csr_k<<<NNODES, 256, 0, stream>>>(row_start, csr_src, z1, as1, ad1, b1, h1);

    // ---- layer 2 ----
    gemm2_k<<<(NNODES + 7) / 8, 256, 0, stream>>>(h1, W2, z2);
    attn2_k<<<(NNODES + 255) / 256, 256, 0, stream>>>(z2, av2, bv2, as2, ad2);
    agg2_csr_k<<<(NNODES + 7) / 8, 256, 0, stream>>>(row_start, csr_src, z2, as2, ad2, b2, out);
}

// Round 3
// 525.766 us; speedup vs baseline: 2.4971x; 1.2883x over previous
//
#include <hip/hip_runtime.h>

#define NNODES 50000
#define NFEAT 256
#define NHID 32
#define NHEADS 8
#define NCLASSES 32
#define NEDGES 800000
#define ETOT (NEDGES + NNODES)   // 850000 with self loops

typedef __attribute__((ext_vector_type(8))) short short8;
typedef __attribute__((ext_vector_type(4))) float f32x4;

__device__ __forceinline__ void get_edge(const int* __restrict__ ei, int e,
                                         int& s, int& d) {
    if (e < NEDGES) { s = ei[e]; d = ei[NEDGES + e]; }
    else            { s = e - NEDGES; d = s; }
}
__device__ __forceinline__ float lrelu(float x) { return x > 0.f ? x : 0.2f * x; }
__device__ __forceinline__ unsigned short f2bf(float f) {   // RNE
    unsigned u = __float_as_uint(f);
    unsigned r = u + 0x7fffu + ((u >> 16) & 1u);
    return (unsigned short)(r >> 16);
}
__device__ __forceinline__ float bflo(unsigned u) { return __uint_as_float(u << 16); }
__device__ __forceinline__ float bfhi(unsigned u) { return __uint_as_float(u & 0xffff0000u); }

// ---------- W1^T -> bf16 [n][k] ----------
__global__ void w1t_k(const float* __restrict__ W1, unsigned short* __restrict__ Wt) {
    int idx = blockIdx.x * 256 + threadIdx.x;      // 65536
    int n = idx >> 8, k = idx & 255;
    Wt[n * 256 + k] = f2bf(W1[k * 256 + n]);
}

// ---------- GEMM1 (MFMA bf16): z1[N,256](bf16) = x @ W1 + b1 ----------
// block = 256 thr = 4 waves; wave w handles rows [bx*64 + w*16, +16), all 256 cols.
__global__ __launch_bounds__(256) void gemm1_mfma_k(
        const float* __restrict__ x, const unsigned short* __restrict__ Wt,
        const float* __restrict__ b, unsigned short* __restrict__ z1) {
    int w = threadIdx.x >> 6, lane = threadIdx.x & 63;
    int quad = lane >> 4, l16 = lane & 15;
    int mA = blockIdx.x * 64 + w * 16 + l16;        // A-frag row for this lane
    int mAl = min(mA, NNODES - 1);

    f32x4 acc[16];
#pragma unroll
    for (int nt = 0; nt < 16; ++nt) acc[nt] = (f32x4){0.f, 0.f, 0.f, 0.f};

    for (int kc = 0; kc < 8; ++kc) {
        int k0 = kc * 32 + quad * 8;
        const float4* xp = (const float4*)(x + (size_t)mAl * 256 + k0);
        float4 a0 = xp[0], a1 = xp[1];
        short8 af;
        af[0] = (short)f2bf(a0.x); af[1] = (short)f2bf(a0.y);
        af[2] = (short)f2bf(a0.z); af[3] = (short)f2bf(a0.w);
        af[4] = (short)f2bf(a1.x); af[5] = (short)f2bf(a1.y);
        af[6] = (short)f2bf(a1.z); af[7] = (short)f2bf(a1.w);
#pragma unroll
        for (int nt = 0; nt < 16; ++nt) {
            int n = nt * 16 + l16;
            short8 bf8 = *(const short8*)(Wt + n * 256 + k0);
            acc[nt] = __builtin_amdgcn_mfma_f32_16x16x32_bf16(af, bf8, acc[nt], 0, 0, 0);
        }
    }
    // epilogue: C/D layout col=lane&15, row=quad*4+reg
    int mrow0 = blockIdx.x * 64 + w * 16 + quad * 4;
#pragma unroll
    for (int nt = 0; nt < 16; ++nt) {
        int n = nt * 16 + l16;
        float bb = b[n];
#pragma unroll
        for (int r = 0; r < 4; ++r) {
            int mr = mrow0 + r;
            if (mr < NNODES) z1[(size_t)mr * 256 + n] = f2bf(acc[nt][r] + bb);
        }
    }
}

// ---------- GEMM2: z2[N,32] = h1[N,256] @ W2[256,32] ----------
__global__ void gemm2_k(const float* __restrict__ h, const float* __restrict__ W,
                        float* __restrict__ z) {
    __shared__ float hs[8][256];
    int n0 = blockIdx.x * 8;
    int t = threadIdx.x;
#pragma unroll
    for (int i = 0; i < 8; ++i) {
        int n = n0 + i;
        hs[i][t] = (n < NNODES) ? h[n * 256 + t] : 0.f;
    }
    __syncthreads();
    int r = t >> 5, c = t & 31;
    float acc = 0.f;
    for (int k = 0; k < 256; ++k) acc += hs[r][k] * W[k * 32 + c];
    int n = n0 + r;
    if (n < NNODES) z[n * 32 + c] = acc;
}

// ---------- attn1: per (node, head) dot with a_src/a_dst (z1 is bf16) ----------
__global__ void attn1_k(const unsigned short* __restrict__ z, const float* __restrict__ av,
                        const float* __restrict__ bv, float* __restrict__ as_,
                        float* __restrict__ ad_) {
    int id = blockIdx.x * blockDim.x + threadIdx.x;
    if (id >= NNODES * NHEADS) return;
    int n = id >> 3, h = id & 7;
    const uint4* zp = (const uint4*)(z + (size_t)n * 256 + h * 32);
    const float* ap = av + h * 32;
    const float* bp = bv + h * 32;
    float s = 0.f, d = 0.f;
#pragma unroll
    for (int q = 0; q < 4; ++q) {
        uint4 u = zp[q];
        int c = q * 8;
        float v;
        v = bflo(u.x); s += v * ap[c + 0]; d += v * bp[c + 0];
        v = bfhi(u.x); s += v * ap[c + 1]; d += v * bp[c + 1];
        v = bflo(u.y); s += v * ap[c + 2]; d += v * bp[c + 2];
        v = bfhi(u.y); s += v * ap[c + 3]; d += v * bp[c + 3];
        v = bflo(u.z); s += v * ap[c + 4]; d += v * bp[c + 4];
        v = bfhi(u.z); s += v * ap[c + 5]; d += v * bp[c + 5];
        v = bflo(u.w); s += v * ap[c + 6]; d += v * bp[c + 6];
        v = bfhi(u.w); s += v * ap[c + 7]; d += v * bp[c + 7];
    }
    as_[id] = s;
    ad_[id] = d;
}

// ---------- attn2: per node ----------
__global__ void attn2_k(const float* __restrict__ z, const float* __restrict__ av,
                        const float* __restrict__ bv, float* __restrict__ as_,
                        float* __restrict__ ad_) {
    int n = blockIdx.x * blockDim.x + threadIdx.x;
    if (n >= NNODES) return;
    float s = 0.f, d = 0.f;
#pragma unroll
    for (int c = 0; c < 32; ++c) { float v = z[n * 32 + c]; s += v * av[c]; d += v * bv[c]; }
    as_[n] = s;
    ad_[n] = d;
}

// ---------- CSR build ----------
__global__ void hist_k(const int* __restrict__ ei, int* __restrict__ deg) {
    int e = blockIdx.x * blockDim.x + threadIdx.x;
    if (e >= ETOT) return;
    int s, d;
    get_edge(ei, e, s, d);
    atomicAdd(&deg[d], 1);
}

// shuffle-based single-block scan (1024 thr = 16 waves)
__global__ void scan_k(const int* __restrict__ deg, int* __restrict__ row_start) {
    __shared__ int wsum[16];
    __shared__ int carry;
    int t = threadIdx.x;
    int lane = t & 63, wid = t >> 6;
    if (t == 0) carry = 0;
    __syncthreads();
    for (int base = 0; base < NNODES; base += 1024) {
        int idx = base + t;
        int v = (idx < NNODES) ? deg[idx] : 0;
        int inc = v;
#pragma unroll
        for (int off = 1; off < 64; off <<= 1) {
            int u = __shfl_up(inc, off, 64);
            if (lane >= off) inc += u;
        }
        if (lane == 63) wsum[wid] = inc;
        __syncthreads();
        if (wid == 0 && lane < 16) {
            int wv = wsum[lane];
#pragma unroll
            for (int off = 1; off < 16; off <<= 1) {
                int u = __shfl_up(wv, off, 64);
                if (lane >= off) wv += u;
            }
            wsum[lane] = wv;
        }
        __syncthreads();
        int woff = (wid == 0) ? 0 : wsum[wid - 1];
        int excl = carry + woff + inc - v;
        if (idx < NNODES) row_start[idx] = excl;
        __syncthreads();                 // wsum reads done before next write / carry update
        if (t == 0) carry += wsum[15];
        __syncthreads();
    }
    if (t == 0) row_start[NNODES] = carry;
}

__global__ void scatter_k(const int* __restrict__ ei, const int* __restrict__ row_start,
                          int* __restrict__ cursor, int* __restrict__ csr_src) {
    int e = blockIdx.x * blockDim.x + threadIdx.x;
    if (e >= ETOT) return;
    int s, d;
    get_edge(ei, e, s, d);
    int pos = atomicAdd(&cursor[d], 1);
    csr_src[row_start[d] + pos] = s;
}

// ---------- fused layer-1 aggregation: one wave per dst (4 dsts/block) ----------
// lane owns 4 channels c0=lane*4; head h = lane>>3. No max-subtraction (logits bounded).
__global__ void agg1_csr_k(const int* __restrict__ row_start, const int* __restrict__ csr_src,
                           const unsigned short* __restrict__ z, const float* __restrict__ as_,
                           const float* __restrict__ ad_, const float* __restrict__ b,
                           float* __restrict__ h1) {
    int wv = threadIdx.x >> 6, lane = threadIdx.x & 63;
    int d = blockIdx.x * 4 + wv;
    int h = lane >> 3;
    int c0 = lane * 4;
    float adh = ad_[d * 8 + h];
    int beg = row_start[d], end = row_start[d + 1];
    float sum = 0.f, a0 = 0.f, a1 = 0.f, a2 = 0.f, a3 = 0.f;
    for (int i = beg; i < end; ++i) {
        int s = csr_src[i];
        float l = lrelu(as_[s * 8 + h] + adh);
        float wgt = __expf(l);
        sum += wgt;
        uint2 zz = *(const uint2*)(z + (size_t)s * 256 + c0);
        a0 += wgt * bflo(zz.x);
        a1 += wgt * bfhi(zz.x);
        a2 += wgt * bflo(zz.y);
        a3 += wgt * bfhi(zz.y);
    }
    float inv = 1.f / sum;
    float4 o;
    o.x = a0 * inv + b[c0 + 0];
    o.y = a1 * inv + b[c0 + 1];
    o.z = a2 * inv + b[c0 + 2];
    o.w = a3 * inv + b[c0 + 3];
    o.x = o.x > 0.f ? o.x : expm1f(o.x);
    o.y = o.y > 0.f ? o.y : expm1f(o.y);
    o.z = o.z > 0.f ? o.z : expm1f(o.z);
    o.w = o.w > 0.f ? o.w : expm1f(o.w);
    *(float4*)(h1 + (size_t)d * 256 + c0) = o;
}

// ---------- fused layer-2 aggregation + bias: 8 dsts/block, 32 lanes each ----------
__global__ void agg2_csr_k(const int* __restrict__ row_start, const int* __restrict__ csr_src,
                           const float* __restrict__ z2, const float* __restrict__ as_,
                           const float* __restrict__ ad_, const float* __restrict__ b,
                           float* __restrict__ out) {
    int g = blockIdx.x * 8 + (threadIdx.x >> 5);
    int c = threadIdx.x & 31;
    if (g >= NNODES) return;
    int beg = row_start[g], end = row_start[g + 1];
    float adn = ad_[g];
    float sum = 0.f, acc = 0.f;
    for (int i = beg; i < end; ++i) {
        int s = csr_src[i];
        float l = lrelu(as_[s] + adn);
        float wgt = __expf(l);
        sum += wgt;
        acc += wgt * z2[s * 32 + c];
    }
    out[g * 32 + c] = acc / sum + b[c];
}

extern "C" void kernel_launch(void* const* d_in, const int* in_sizes, int n_in,
                              void* d_out, int out_size, void* d_ws, size_t ws_size,
                              hipStream_t stream) {
    const float* x   = (const float*)d_in[0];
    const int*   ei  = (const int*)d_in[1];
    const float* W1  = (const float*)d_in[2];
    const float* av1 = (const float*)d_in[3];
    const float* bv1 = (const float*)d_in[4];
    const float* b1  = (const float*)d_in[5];
    const float* W2  = (const float*)d_in[6];
    const float* av2 = (const float*)d_in[7];
    const float* bv2 = (const float*)d_in[8];
    const float* b2  = (const float*)d_in[9];
    float* out = (float*)d_out;

    // workspace layout (4-byte units)
    unsigned short* z1 = (unsigned short*)d_ws;          // 12.8M bf16 = 6.4M u32
    float* h1  = (float*)d_ws + 6400000;                 // 12,800,000
    float* as1 = h1 + 12800000;                          // 400,000
    float* ad1 = as1 + 400000;                           // 400,000
    float* z2  = ad1 + 400000;                           // 1,600,000
    float* as2 = z2 + 1600000;                           // 50,000
    float* ad2 = as2 + 50000;                            // 50,000
    unsigned short* Wt = (unsigned short*)(ad2 + 50000); // 65536 bf16 = 32768 u32
    int* deg       = (int*)(ad2 + 50000) + 32768;        // 50,000
    int* cursor    = deg + 50000;                        // 50,000
    int* row_start = cursor + 50000;                     // 50,001
    int* csr_src   = row_start + 50001;                  // 850,000

    hipMemsetAsync(deg, 0, (size_t)100000 * 4, stream);  // deg + cursor

    // ---- CSR build (shared by both layers) ----
    hist_k<<<(ETOT + 255) / 256, 256, 0, stream>>>(ei, deg);
    scan_k<<<1, 1024, 0, stream>>>(deg, row_start);
    scatter_k<<<(ETOT + 255) / 256, 256, 0, stream>>>(ei, row_start, cursor, csr_src);

    // ---- layer 1 ----
    w1t_k<<<256, 256, 0, stream>>>(W1, Wt);
    gemm1_mfma_k<<<(NNODES + 63) / 64, 256, 0, stream>>>(x, Wt, b1, z1);
    attn1_k<<<(NNODES * NHEADS + 255) / 256, 256, 0, stream>>>(z1, av1, bv1, as1, ad1);
    agg1_csr_k<<<(NNODES + 3) / 4, 256, 0, stream>>>(row_start, csr_src, z1, as1, ad1, b1, h1);

    // ---- layer 2 ----
    gemm2_k<<<(NNODES + 7) / 8, 256, 0, stream>>>(h1, W2, z2);
    attn2_k<<<(NNODES + 255) / 256, 256, 0, stream>>>(z2, av2, bv2, as2, ad2);
    agg2_csr_k<<<(NNODES + 7) / 8, 256, 0, stream>>>(row_start, csr_src, z2, as2, ad2, b2, out);
}

// Round 4
// 409.767 us; speedup vs baseline: 3.2040x; 1.2831x over previous
//
#include <hip/hip_runtime.h>

#define NNODES 50000
#define NFEAT 256
#define NHID 32
#define NHEADS 8
#define NCLASSES 32
#define NEDGES 800000
#define ETOT (NEDGES + NNODES)   // 850000 with self loops

typedef __attribute__((ext_vector_type(8))) short short8;
typedef __attribute__((ext_vector_type(4))) float f32x4;

__device__ __forceinline__ void get_edge(const int* __restrict__ ei, int e,
                                         int& s, int& d) {
    if (e < NEDGES) { s = ei[e]; d = ei[NEDGES + e]; }
    else            { s = e - NEDGES; d = s; }
}
__device__ __forceinline__ float lrelu(float x) { return x > 0.f ? x : 0.2f * x; }
__device__ __forceinline__ unsigned short f2bf(float f) {   // RNE
    unsigned u = __float_as_uint(f);
    unsigned r = u + 0x7fffu + ((u >> 16) & 1u);
    return (unsigned short)(r >> 16);
}
__device__ __forceinline__ float bflo(unsigned u) { return __uint_as_float(u << 16); }
__device__ __forceinline__ float bfhi(unsigned u) { return __uint_as_float(u & 0xffff0000u); }

// ---------- weight prep: W1^T and W2^T -> bf16 [n][k] ----------
__global__ void wprep_k(const float* __restrict__ W1, const float* __restrict__ W2,
                        unsigned short* __restrict__ W1t, unsigned short* __restrict__ W2t) {
    int idx = blockIdx.x * 256 + threadIdx.x;
    if (idx < 65536) {                       // W1 [256,256] -> W1t[n][k]
        int n = idx >> 8, k = idx & 255;
        W1t[n * 256 + k] = f2bf(W1[k * 256 + n]);
    } else if (idx < 65536 + 8192) {         // W2 [256,32] -> W2t[n][k]
        int j = idx - 65536;
        int n = j >> 8, k = j & 255;
        W2t[n * 256 + k] = f2bf(W2[k * 32 + n]);
    }
}

// ---------- GEMM1 (MFMA bf16) + fused attn1 epilogue ----------
// wave w: rows [bx*64 + w*16, +16), cols 0..255. z1 bf16 (no bias: ref adds b1 post-agg).
__global__ __launch_bounds__(256) void gemm1_mfma_k(
        const float* __restrict__ x, const unsigned short* __restrict__ Wt,
        const float* __restrict__ av, const float* __restrict__ bv,
        unsigned short* __restrict__ z1, float* __restrict__ as_, float* __restrict__ ad_) {
    int w = threadIdx.x >> 6, lane = threadIdx.x & 63;
    int quad = lane >> 4, l16 = lane & 15;
    int mA = blockIdx.x * 64 + w * 16 + l16;
    int mAl = min(mA, NNODES - 1);

    f32x4 acc[16];
#pragma unroll
    for (int nt = 0; nt < 16; ++nt) acc[nt] = (f32x4){0.f, 0.f, 0.f, 0.f};

    for (int kc = 0; kc < 8; ++kc) {
        int k0 = kc * 32 + quad * 8;
        const float4* xp = (const float4*)(x + (size_t)mAl * 256 + k0);
        float4 a0 = xp[0], a1 = xp[1];
        short8 af;
        af[0] = (short)f2bf(a0.x); af[1] = (short)f2bf(a0.y);
        af[2] = (short)f2bf(a0.z); af[3] = (short)f2bf(a0.w);
        af[4] = (short)f2bf(a1.x); af[5] = (short)f2bf(a1.y);
        af[6] = (short)f2bf(a1.z); af[7] = (short)f2bf(a1.w);
#pragma unroll
        for (int nt = 0; nt < 16; ++nt) {
            int n = nt * 16 + l16;
            short8 bf8 = *(const short8*)(Wt + n * 256 + k0);
            acc[nt] = __builtin_amdgcn_mfma_f32_16x16x32_bf16(af, bf8, acc[nt], 0, 0, 0);
        }
    }
    // C/D layout: col = nt*16 + l16, row = mrow0 + reg
    int mrow0 = blockIdx.x * 64 + w * 16 + quad * 4;
#pragma unroll
    for (int nt = 0; nt < 16; ++nt) {
        int n = nt * 16 + l16;
#pragma unroll
        for (int r = 0; r < 4; ++r) {
            int mr = mrow0 + r;
            if (mr < NNODES) z1[(size_t)mr * 256 + n] = f2bf(acc[nt][r]);
        }
    }
    // fused attn1: head h covers cols [h*32,(h+1)*32) = nt in {2h, 2h+1}
#pragma unroll
    for (int h = 0; h < 8; ++h) {
        float av0 = av[(2 * h) * 16 + l16], av1v = av[(2 * h + 1) * 16 + l16];
        float bv0 = bv[(2 * h) * 16 + l16], bv1v = bv[(2 * h + 1) * 16 + l16];
#pragma unroll
        for (int r = 0; r < 4; ++r) {
            float pa = acc[2 * h][r] * av0 + acc[2 * h + 1][r] * av1v;
            float pb = acc[2 * h][r] * bv0 + acc[2 * h + 1][r] * bv1v;
#pragma unroll
            for (int off = 1; off < 16; off <<= 1) {
                pa += __shfl_xor(pa, off, 64);
                pb += __shfl_xor(pb, off, 64);
            }
            int mr = mrow0 + r;
            if (l16 == 0 && mr < NNODES) { as_[mr * 8 + h] = pa; ad_[mr * 8 + h] = pb; }
        }
    }
}

// ---------- GEMM2 (MFMA bf16) + fused attn2 epilogue ----------
__global__ __launch_bounds__(256) void gemm2_mfma_k(
        const unsigned short* __restrict__ h1, const unsigned short* __restrict__ Wt,
        const float* __restrict__ av, const float* __restrict__ bv,
        float* __restrict__ z2, float* __restrict__ as_, float* __restrict__ ad_) {
    int w = threadIdx.x >> 6, lane = threadIdx.x & 63;
    int quad = lane >> 4, l16 = lane & 15;
    int mA = blockIdx.x * 64 + w * 16 + l16;
    int mAl = min(mA, NNODES - 1);

    f32x4 acc[2];
    acc[0] = (f32x4){0.f, 0.f, 0.f, 0.f};
    acc[1] = (f32x4){0.f, 0.f, 0.f, 0.f};
    for (int kc = 0; kc < 8; ++kc) {
        int k0 = kc * 32 + quad * 8;
        short8 af = *(const short8*)(h1 + (size_t)mAl * 256 + k0);
#pragma unroll
        for (int nt = 0; nt < 2; ++nt) {
            short8 bf8 = *(const short8*)(Wt + (nt * 16 + l16) * 256 + k0);
            acc[nt] = __builtin_amdgcn_mfma_f32_16x16x32_bf16(af, bf8, acc[nt], 0, 0, 0);
        }
    }
    int mrow0 = blockIdx.x * 64 + w * 16 + quad * 4;
    float av0 = av[l16], av1v = av[16 + l16];
    float bv0 = bv[l16], bv1v = bv[16 + l16];
#pragma unroll
    for (int r = 0; r < 4; ++r) {
        int mr = mrow0 + r;
        float pa = acc[0][r] * av0 + acc[1][r] * av1v;
        float pb = acc[0][r] * bv0 + acc[1][r] * bv1v;
#pragma unroll
        for (int off = 1; off < 16; off <<= 1) {
            pa += __shfl_xor(pa, off, 64);
            pb += __shfl_xor(pb, off, 64);
        }
        if (mr < NNODES) {
            z2[(size_t)mr * 32 + l16] = acc[0][r];
            z2[(size_t)mr * 32 + 16 + l16] = acc[1][r];
            if (l16 == 0) { as_[mr] = pa; ad_[mr] = pb; }
        }
    }
}

// ---------- CSR build ----------
__global__ void hist_k(const int* __restrict__ ei, int* __restrict__ deg) {
    int e = blockIdx.x * blockDim.x + threadIdx.x;
    if (e >= ETOT) return;
    int s, d;
    get_edge(ei, e, s, d);
    atomicAdd(&deg[d], 1);
}

__global__ void scan_k(const int* __restrict__ deg, int* __restrict__ row_start) {
    __shared__ int wsum[16];
    __shared__ int carry;
    int t = threadIdx.x;
    int lane = t & 63, wid = t >> 6;
    if (t == 0) carry = 0;
    __syncthreads();
    for (int base = 0; base < NNODES; base += 1024) {
        int idx = base + t;
        int v = (idx < NNODES) ? deg[idx] : 0;
        int inc = v;
#pragma unroll
        for (int off = 1; off < 64; off <<= 1) {
            int u = __shfl_up(inc, off, 64);
            if (lane >= off) inc += u;
        }
        if (lane == 63) wsum[wid] = inc;
        __syncthreads();
        if (wid == 0 && lane < 16) {
            int wv = wsum[lane];
#pragma unroll
            for (int off = 1; off < 16; off <<= 1) {
                int u = __shfl_up(wv, off, 64);
                if (lane >= off) wv += u;
            }
            wsum[lane] = wv;
        }
        __syncthreads();
        int woff = (wid == 0) ? 0 : wsum[wid - 1];
        int excl = carry + woff + inc - v;
        if (idx < NNODES) row_start[idx] = excl;
        __syncthreads();
        if (t == 0) carry += wsum[15];
        __syncthreads();
    }
    if (t == 0) row_start[NNODES] = carry;
}

__global__ void scatter_k(const int* __restrict__ ei, const int* __restrict__ row_start,
                          int* __restrict__ cursor, int* __restrict__ csr_src) {
    int e = blockIdx.x * blockDim.x + threadIdx.x;
    if (e >= ETOT) return;
    int s, d;
    get_edge(ei, e, s, d);
    int pos = atomicAdd(&cursor[d], 1);
    csr_src[row_start[d] + pos] = s;
}

// ---------- fused layer-1 aggregation: one wave per dst, 4x edge unroll ----------
__global__ void agg1_csr_k(const int* __restrict__ row_start, const int* __restrict__ csr_src,
                           const unsigned short* __restrict__ z, const float* __restrict__ as_,
                           const float* __restrict__ ad_, const float* __restrict__ b,
                           unsigned short* __restrict__ h1) {
    int wv = threadIdx.x >> 6, lane = threadIdx.x & 63;
    int d = blockIdx.x * 4 + wv;
    int h = lane >> 3;
    int c0 = lane * 4;
    float adh = ad_[d * 8 + h];
    int beg = row_start[d], end = row_start[d + 1];
    float sum = 0.f, a0 = 0.f, a1 = 0.f, a2 = 0.f, a3 = 0.f;
    int i = beg;
    for (; i + 4 <= end; i += 4) {
        int s0 = csr_src[i], s1 = csr_src[i + 1], s2 = csr_src[i + 2], s3 = csr_src[i + 3];
        float w0 = __expf(lrelu(as_[s0 * 8 + h] + adh));
        float w1 = __expf(lrelu(as_[s1 * 8 + h] + adh));
        float w2 = __expf(lrelu(as_[s2 * 8 + h] + adh));
        float w3 = __expf(lrelu(as_[s3 * 8 + h] + adh));
        uint2 q0 = *(const uint2*)(z + (size_t)s0 * 256 + c0);
        uint2 q1 = *(const uint2*)(z + (size_t)s1 * 256 + c0);
        uint2 q2 = *(const uint2*)(z + (size_t)s2 * 256 + c0);
        uint2 q3 = *(const uint2*)(z + (size_t)s3 * 256 + c0);
        sum += (w0 + w1) + (w2 + w3);
        a0 += w0 * bflo(q0.x) + w1 * bflo(q1.x) + w2 * bflo(q2.x) + w3 * bflo(q3.x);
        a1 += w0 * bfhi(q0.x) + w1 * bfhi(q1.x) + w2 * bfhi(q2.x) + w3 * bfhi(q3.x);
        a2 += w0 * bflo(q0.y) + w1 * bflo(q1.y) + w2 * bflo(q2.y) + w3 * bflo(q3.y);
        a3 += w0 * bfhi(q0.y) + w1 * bfhi(q1.y) + w2 * bfhi(q2.y) + w3 * bfhi(q3.y);
    }
    for (; i < end; ++i) {
        int s = csr_src[i];
        float wgt = __expf(lrelu(as_[s * 8 + h] + adh));
        uint2 zz = *(const uint2*)(z + (size_t)s * 256 + c0);
        sum += wgt;
        a0 += wgt * bflo(zz.x);
        a1 += wgt * bfhi(zz.x);
        a2 += wgt * bflo(zz.y);
        a3 += wgt * bfhi(zz.y);
    }
    float inv = 1.f / sum;
    float o0 = a0 * inv + b[c0 + 0];
    float o1 = a1 * inv + b[c0 + 1];
    float o2 = a2 * inv + b[c0 + 2];
    float o3 = a3 * inv + b[c0 + 3];
    o0 = o0 > 0.f ? o0 : expm1f(o0);
    o1 = o1 > 0.f ? o1 : expm1f(o1);
    o2 = o2 > 0.f ? o2 : expm1f(o2);
    o3 = o3 > 0.f ? o3 : expm1f(o3);
    uint2 pk;
    pk.x = (unsigned)f2bf(o0) | ((unsigned)f2bf(o1) << 16);
    pk.y = (unsigned)f2bf(o2) | ((unsigned)f2bf(o3) << 16);
    *(uint2*)(h1 + (size_t)d * 256 + c0) = pk;
}

// ---------- fused layer-2 aggregation + bias: 8 dsts/block, 32 lanes each, 4x unroll ----------
__global__ void agg2_csr_k(const int* __restrict__ row_start, const int* __restrict__ csr_src,
                           const float* __restrict__ z2, const float* __restrict__ as_,
                           const float* __restrict__ ad_, const float* __restrict__ b,
                           float* __restrict__ out) {
    int g = blockIdx.x * 8 + (threadIdx.x >> 5);
    int c = threadIdx.x & 31;
    if (g >= NNODES) return;
    int beg = row_start[g], end = row_start[g + 1];
    float adn = ad_[g];
    float sum = 0.f, acc = 0.f;
    int i = beg;
    for (; i + 4 <= end; i += 4) {
        int s0 = csr_src[i], s1 = csr_src[i + 1], s2 = csr_src[i + 2], s3 = csr_src[i + 3];
        float w0 = __expf(lrelu(as_[s0] + adn));
        float w1 = __expf(lrelu(as_[s1] + adn));
        float w2 = __expf(lrelu(as_[s2] + adn));
        float w3 = __expf(lrelu(as_[s3] + adn));
        float v0 = z2[(size_t)s0 * 32 + c];
        float v1 = z2[(size_t)s1 * 32 + c];
        float v2 = z2[(size_t)s2 * 32 + c];
        float v3 = z2[(size_t)s3 * 32 + c];
        sum += (w0 + w1) + (w2 + w3);
        acc += w0 * v0 + w1 * v1 + w2 * v2 + w3 * v3;
    }
    for (; i < end; ++i) {
        int s = csr_src[i];
        float wgt = __expf(lrelu(as_[s] + adn));
        sum += wgt;
        acc += wgt * z2[(size_t)s * 32 + c];
    }
    out[g * 32 + c] = acc / sum + b[c];
}

extern "C" void kernel_launch(void* const* d_in, const int* in_sizes, int n_in,
                              void* d_out, int out_size, void* d_ws, size_t ws_size,
                              hipStream_t stream) {
    const float* x   = (const float*)d_in[0];
    const int*   ei  = (const int*)d_in[1];
    const float* W1  = (const float*)d_in[2];
    const float* av1 = (const float*)d_in[3];
    const float* bv1 = (const float*)d_in[4];
    const float* b1  = (const float*)d_in[5];
    const float* W2  = (const float*)d_in[6];
    const float* av2 = (const float*)d_in[7];
    const float* bv2 = (const float*)d_in[8];
    const float* b2  = (const float*)d_in[9];
    float* out = (float*)d_out;

    // workspace layout (4-byte units)
    unsigned short* z1 = (unsigned short*)d_ws;            // 12.8M bf16 = 6.4M u32
    unsigned short* h1 = (unsigned short*)((float*)d_ws + 6400000);  // 12.8M bf16 = 6.4M u32
    float* as1 = (float*)d_ws + 12800000;                  // 400,000
    float* ad1 = as1 + 400000;                             // 400,000
    float* z2  = ad1 + 400000;                             // 1,600,000
    float* as2 = z2 + 1600000;                             // 50,000
    float* ad2 = as2 + 50000;                              // 50,000
    unsigned short* W1t = (unsigned short*)(ad2 + 50000);  // 65536 bf16 = 32768 u32
    unsigned short* W2t = (unsigned short*)(ad2 + 50000) + 65536;  // 8192 bf16 = 4096 u32
    int* deg       = (int*)(ad2 + 50000) + 36864;          // 50,000
    int* cursor    = deg + 50000;                          // 50,000
    int* row_start = cursor + 50000;                       // 50,001
    int* csr_src   = row_start + 50001;                    // 850,000

    hipMemsetAsync(deg, 0, (size_t)100000 * 4, stream);   // deg + cursor

    // ---- CSR build (shared by both layers) ----
    hist_k<<<(ETOT + 255) / 256, 256, 0, stream>>>(ei, deg);
    scan_k<<<1, 1024, 0, stream>>>(deg, row_start);
    scatter_k<<<(ETOT + 255) / 256, 256, 0, stream>>>(ei, row_start, cursor, csr_src);

    // ---- layer 1 ----
    wprep_k<<<288, 256, 0, stream>>>(W1, W2, W1t, W2t);
    gemm1_mfma_k<<<(NNODES + 63) / 64, 256, 0, stream>>>(x, W1t, av1, bv1, z1, as1, ad1);
    agg1_csr_k<<<(NNODES + 3) / 4, 256, 0, stream>>>(row_start, csr_src, z1, as1, ad1, b1, h1);

    // ---- layer 2 ----
    gemm2_mfma_k<<<(NNODES + 63) / 64, 256, 0, stream>>>(h1, W2t, av2, bv2, z2, as2, ad2);
    agg2_csr_k<<<(NNODES + 7) / 8, 256, 0, stream>>>(row_start, csr_src, z2, as2, ad2, b2, out);
}

// Round 5
// 366.088 us; speedup vs baseline: 3.5863x; 1.1193x over previous
//
#include <hip/hip_runtime.h>

#define NNODES 50000
#define NFEAT 256
#define NHID 32
#define NHEADS 8
#define NCLASSES 32
#define NEDGES 800000
#define ETOT (NEDGES + NNODES)   // 850000 with self loops

typedef __attribute__((ext_vector_type(8))) short short8;
typedef __attribute__((ext_vector_type(4))) float f32x4;

__device__ __forceinline__ void get_edge(const int* __restrict__ ei, int e,
                                         int& s, int& d) {
    if (e < NEDGES) { s = ei[e]; d = ei[NEDGES + e]; }
    else            { s = e - NEDGES; d = s; }
}
__device__ __forceinline__ float lrelu(float x) { return x > 0.f ? x : 0.2f * x; }
__device__ __forceinline__ unsigned short f2bf(float f) {   // RNE
    unsigned u = __float_as_uint(f);
    unsigned r = u + 0x7fffu + ((u >> 16) & 1u);
    return (unsigned short)(r >> 16);
}
__device__ __forceinline__ float bflo(unsigned u) { return __uint_as_float(u << 16); }
__device__ __forceinline__ float bfhi(unsigned u) { return __uint_as_float(u & 0xffff0000u); }

// ---------- weight prep: fragment-ordered bf16 B-operands ----------
// W1frag slot s in [0, 8192): kc=s>>10, r=s&1023, nt=r>>6, lane=r&63,
//   l16=lane&15, quad=lane>>4; n=nt*16+l16, k0=kc*32+quad*8; 8 shorts = W1[k0+j][n].
// W2frag slot g in [0, 1024): kc=g>>7, r=g&127, nt=r>>6, lane=r&63; n=nt*16+l16 (<32).
__global__ void wprep_k(const float* __restrict__ W1, const float* __restrict__ W2,
                        short8* __restrict__ W1frag, short8* __restrict__ W2frag) {
    int idx = blockIdx.x * 256 + threadIdx.x;
    if (idx < 8192) {
        int kc = idx >> 10, r = idx & 1023;
        int nt = r >> 6, lane = r & 63;
        int l16 = lane & 15, quad = lane >> 4;
        int n = nt * 16 + l16, k0 = kc * 32 + quad * 8;
        short8 v;
#pragma unroll
        for (int j = 0; j < 8; ++j) v[j] = (short)f2bf(W1[(k0 + j) * 256 + n]);
        W1frag[idx] = v;
    } else if (idx < 8192 + 1024) {
        int g = idx - 8192;
        int kc = g >> 7, r = g & 127;
        int nt = r >> 6, lane = r & 63;
        int l16 = lane & 15, quad = lane >> 4;
        int n = nt * 16 + l16, k0 = kc * 32 + quad * 8;
        short8 v;
#pragma unroll
        for (int j = 0; j < 8; ++j) v[j] = (short)f2bf(W2[(k0 + j) * 32 + n]);
        W2frag[g] = v;
    }
}

// ---------- GEMM1 (MFMA bf16, LDS-staged B) + fused attn1 epilogue ----------
// block = 256 thr = 4 waves; wave w: rows [bx*64 + w*16, +16), cols 0..255.
__global__ __launch_bounds__(256) void gemm1_mfma_k(
        const float* __restrict__ x, const short8* __restrict__ Wfrag,
        const float* __restrict__ av, const float* __restrict__ bv,
        unsigned short* __restrict__ z1, float* __restrict__ as_, float* __restrict__ ad_) {
    __shared__ short8 wlds[1024];    // 16 KB: one kc-slice, fragment-ordered
    int t = threadIdx.x;
    int w = t >> 6, lane = t & 63;
    int quad = lane >> 4, l16 = lane & 15;
    int mA = blockIdx.x * 64 + w * 16 + l16;
    int mAl = min(mA, NNODES - 1);

    f32x4 acc[16];
#pragma unroll
    for (int nt = 0; nt < 16; ++nt) acc[nt] = (f32x4){0.f, 0.f, 0.f, 0.f};

    short8 pf[4];
#pragma unroll
    for (int j = 0; j < 4; ++j) pf[j] = Wfrag[j * 256 + t];   // kc=0 slice

    for (int kc = 0; kc < 8; ++kc) {
        __syncthreads();             // previous slice's reads complete
#pragma unroll
        for (int j = 0; j < 4; ++j) wlds[j * 256 + t] = pf[j];
        __syncthreads();
        if (kc < 7) {
#pragma unroll
            for (int j = 0; j < 4; ++j) pf[j] = Wfrag[(kc + 1) * 1024 + j * 256 + t];
        }
        int k0 = kc * 32 + quad * 8;
        const float4* xp = (const float4*)(x + (size_t)mAl * 256 + k0);
        float4 a0 = xp[0], a1 = xp[1];
        short8 af;
        af[0] = (short)f2bf(a0.x); af[1] = (short)f2bf(a0.y);
        af[2] = (short)f2bf(a0.z); af[3] = (short)f2bf(a0.w);
        af[4] = (short)f2bf(a1.x); af[5] = (short)f2bf(a1.y);
        af[6] = (short)f2bf(a1.z); af[7] = (short)f2bf(a1.w);
#pragma unroll
        for (int nt = 0; nt < 16; ++nt) {
            short8 bf8 = wlds[nt * 64 + lane];
            acc[nt] = __builtin_amdgcn_mfma_f32_16x16x32_bf16(af, bf8, acc[nt], 0, 0, 0);
        }
    }
    // C/D layout: col = nt*16 + l16, row = mrow0 + reg
    int mrow0 = blockIdx.x * 64 + w * 16 + quad * 4;
#pragma unroll
    for (int nt = 0; nt < 16; ++nt) {
        int n = nt * 16 + l16;
#pragma unroll
        for (int r = 0; r < 4; ++r) {
            int mr = mrow0 + r;
            if (mr < NNODES) z1[(size_t)mr * 256 + n] = f2bf(acc[nt][r]);
        }
    }
    // fused attn1: head h covers cols [h*32,(h+1)*32) = nt in {2h, 2h+1}
#pragma unroll
    for (int h = 0; h < 8; ++h) {
        float av0 = av[(2 * h) * 16 + l16], av1v = av[(2 * h + 1) * 16 + l16];
        float bv0 = bv[(2 * h) * 16 + l16], bv1v = bv[(2 * h + 1) * 16 + l16];
#pragma unroll
        for (int r = 0; r < 4; ++r) {
            float pa = acc[2 * h][r] * av0 + acc[2 * h + 1][r] * av1v;
            float pb = acc[2 * h][r] * bv0 + acc[2 * h + 1][r] * bv1v;
#pragma unroll
            for (int off = 1; off < 16; off <<= 1) {
                pa += __shfl_xor(pa, off, 64);
                pb += __shfl_xor(pb, off, 64);
            }
            int mr = mrow0 + r;
            if (l16 == 0 && mr < NNODES) { as_[mr * 8 + h] = pa; ad_[mr * 8 + h] = pb; }
        }
    }
}

// ---------- GEMM2 (MFMA bf16, coalesced fragment B from global/L1) + fused attn2 ----------
__global__ __launch_bounds__(256) void gemm2_mfma_k(
        const unsigned short* __restrict__ h1, const short8* __restrict__ Wfrag,
        const float* __restrict__ av, const float* __restrict__ bv,
        float* __restrict__ z2, float* __restrict__ as_, float* __restrict__ ad_) {
    int w = threadIdx.x >> 6, lane = threadIdx.x & 63;
    int quad = lane >> 4, l16 = lane & 15;
    int mA = blockIdx.x * 64 + w * 16 + l16;
    int mAl = min(mA, NNODES - 1);

    f32x4 acc[2];
    acc[0] = (f32x4){0.f, 0.f, 0.f, 0.f};
    acc[1] = (f32x4){0.f, 0.f, 0.f, 0.f};
    for (int kc = 0; kc < 8; ++kc) {
        int k0 = kc * 32 + quad * 8;
        short8 af = *(const short8*)(h1 + (size_t)mAl * 256 + k0);
#pragma unroll
        for (int nt = 0; nt < 2; ++nt) {
            short8 bf8 = Wfrag[kc * 128 + nt * 64 + lane];
            acc[nt] = __builtin_amdgcn_mfma_f32_16x16x32_bf16(af, bf8, acc[nt], 0, 0, 0);
        }
    }
    int mrow0 = blockIdx.x * 64 + w * 16 + quad * 4;
    float av0 = av[l16], av1v = av[16 + l16];
    float bv0 = bv[l16], bv1v = bv[16 + l16];
#pragma unroll
    for (int r = 0; r < 4; ++r) {
        int mr = mrow0 + r;
        float pa = acc[0][r] * av0 + acc[1][r] * av1v;
        float pb = acc[0][r] * bv0 + acc[1][r] * bv1v;
#pragma unroll
        for (int off = 1; off < 16; off <<= 1) {
            pa += __shfl_xor(pa, off, 64);
            pb += __shfl_xor(pb, off, 64);
        }
        if (mr < NNODES) {
            z2[(size_t)mr * 32 + l16] = acc[0][r];
            z2[(size_t)mr * 32 + 16 + l16] = acc[1][r];
            if (l16 == 0) { as_[mr] = pa; ad_[mr] = pb; }
        }
    }
}

// ---------- CSR build ----------
__global__ void hist_k(const int* __restrict__ ei, int* __restrict__ deg) {
    int e = blockIdx.x * blockDim.x + threadIdx.x;
    if (e >= ETOT) return;
    int s, d;
    get_edge(ei, e, s, d);
    atomicAdd(&deg[d], 1);
}

__global__ void scan_k(const int* __restrict__ deg, int* __restrict__ row_start) {
    __shared__ int wsum[16];
    __shared__ int carry;
    int t = threadIdx.x;
    int lane = t & 63, wid = t >> 6;
    if (t == 0) carry = 0;
    __syncthreads();
    for (int base = 0; base < NNODES; base += 1024) {
        int idx = base + t;
        int v = (idx < NNODES) ? deg[idx] : 0;
        int inc = v;
#pragma unroll
        for (int off = 1; off < 64; off <<= 1) {
            int u = __shfl_up(inc, off, 64);
            if (lane >= off) inc += u;
        }
        if (lane == 63) wsum[wid] = inc;
        __syncthreads();
        if (wid == 0 && lane < 16) {
            int wv = wsum[lane];
#pragma unroll
            for (int off = 1; off < 16; off <<= 1) {
                int u = __shfl_up(wv, off, 64);
                if (lane >= off) wv += u;
            }
            wsum[lane] = wv;
        }
        __syncthreads();
        int woff = (wid == 0) ? 0 : wsum[wid - 1];
        int excl = carry + woff + inc - v;
        if (idx < NNODES) row_start[idx] = excl;
        __syncthreads();
        if (t == 0) carry += wsum[15];
        __syncthreads();
    }
    if (t == 0) row_start[NNODES] = carry;
}

__global__ void scatter_k(const int* __restrict__ ei, const int* __restrict__ row_start,
                          int* __restrict__ cursor, int* __restrict__ csr_src) {
    int e = blockIdx.x * blockDim.x + threadIdx.x;
    if (e >= ETOT) return;
    int s, d;
    get_edge(ei, e, s, d);
    int pos = atomicAdd(&cursor[d], 1);
    csr_src[row_start[d] + pos] = s;
}

// ---------- fused layer-1 aggregation: one wave per dst, 4x edge unroll ----------
__global__ void agg1_csr_k(const int* __restrict__ row_start, const int* __restrict__ csr_src,
                           const unsigned short* __restrict__ z, const float* __restrict__ as_,
                           const float* __restrict__ ad_, const float* __restrict__ b,
                           unsigned short* __restrict__ h1) {
    int wv = threadIdx.x >> 6, lane = threadIdx.x & 63;
    int d = blockIdx.x * 4 + wv;
    int h = lane >> 3;
    int c0 = lane * 4;
    float adh = ad_[d * 8 + h];
    int beg = row_start[d], end = row_start[d + 1];
    float sum = 0.f, a0 = 0.f, a1 = 0.f, a2 = 0.f, a3 = 0.f;
    int i = beg;
    for (; i + 4 <= end; i += 4) {
        int s0 = csr_src[i], s1 = csr_src[i + 1], s2 = csr_src[i + 2], s3 = csr_src[i + 3];
        float w0 = __expf(lrelu(as_[s0 * 8 + h] + adh));
        float w1 = __expf(lrelu(as_[s1 * 8 + h] + adh));
        float w2 = __expf(lrelu(as_[s2 * 8 + h] + adh));
        float w3 = __expf(lrelu(as_[s3 * 8 + h] + adh));
        uint2 q0 = *(const uint2*)(z + (size_t)s0 * 256 + c0);
        uint2 q1 = *(const uint2*)(z + (size_t)s1 * 256 + c0);
        uint2 q2 = *(const uint2*)(z + (size_t)s2 * 256 + c0);
        uint2 q3 = *(const uint2*)(z + (size_t)s3 * 256 + c0);
        sum += (w0 + w1) + (w2 + w3);
        a0 += w0 * bflo(q0.x) + w1 * bflo(q1.x) + w2 * bflo(q2.x) + w3 * bflo(q3.x);
        a1 += w0 * bfhi(q0.x) + w1 * bfhi(q1.x) + w2 * bfhi(q2.x) + w3 * bfhi(q3.x);
        a2 += w0 * bflo(q0.y) + w1 * bflo(q1.y) + w2 * bflo(q2.y) + w3 * bflo(q3.y);
        a3 += w0 * bfhi(q0.y) + w1 * bfhi(q1.y) + w2 * bfhi(q2.y) + w3 * bfhi(q3.y);
    }
    for (; i < end; ++i) {
        int s = csr_src[i];
        float wgt = __expf(lrelu(as_[s * 8 + h] + adh));
        uint2 zz = *(const uint2*)(z + (size_t)s * 256 + c0);
        sum += wgt;
        a0 += wgt * bflo(zz.x);
        a1 += wgt * bfhi(zz.x);
        a2 += wgt * bflo(zz.y);
        a3 += wgt * bfhi(zz.y);
    }
    float inv = 1.f / sum;
    float o0 = a0 * inv + b[c0 + 0];
    float o1 = a1 * inv + b[c0 + 1];
    float o2 = a2 * inv + b[c0 + 2];
    float o3 = a3 * inv + b[c0 + 3];
    o0 = o0 > 0.f ? o0 : expm1f(o0);
    o1 = o1 > 0.f ? o1 : expm1f(o1);
    o2 = o2 > 0.f ? o2 : expm1f(o2);
    o3 = o3 > 0.f ? o3 : expm1f(o3);
    uint2 pk;
    pk.x = (unsigned)f2bf(o0) | ((unsigned)f2bf(o1) << 16);
    pk.y = (unsigned)f2bf(o2) | ((unsigned)f2bf(o3) << 16);
    *(uint2*)(h1 + (size_t)d * 256 + c0) = pk;
}

// ---------- fused layer-2 aggregation + bias: 8 dsts/block, 32 lanes each, 4x unroll ----------
__global__ void agg2_csr_k(const int* __restrict__ row_start, const int* __restrict__ csr_src,
                           const float* __restrict__ z2, const float* __restrict__ as_,
                           const float* __restrict__ ad_, const float* __restrict__ b,
                           float* __restrict__ out) {
    int g = blockIdx.x * 8 + (threadIdx.x >> 5);
    int c = threadIdx.x & 31;
    if (g >= NNODES) return;
    int beg = row_start[g], end = row_start[g + 1];
    float adn = ad_[g];
    float sum = 0.f, acc = 0.f;
    int i = beg;
    for (; i + 4 <= end; i += 4) {
        int s0 = csr_src[i], s1 = csr_src[i + 1], s2 = csr_src[i + 2], s3 = csr_src[i + 3];
        float w0 = __expf(lrelu(as_[s0] + adn));
        float w1 = __expf(lrelu(as_[s1] + adn));
        float w2 = __expf(lrelu(as_[s2] + adn));
        float w3 = __expf(lrelu(as_[s3] + adn));
        float v0 = z2[(size_t)s0 * 32 + c];
        float v1 = z2[(size_t)s1 * 32 + c];
        float v2 = z2[(size_t)s2 * 32 + c];
        float v3 = z2[(size_t)s3 * 32 + c];
        sum += (w0 + w1) + (w2 + w3);
        acc += w0 * v0 + w1 * v1 + w2 * v2 + w3 * v3;
    }
    for (; i < end; ++i) {
        int s = csr_src[i];
        float wgt = __expf(lrelu(as_[s] + adn));
        sum += wgt;
        acc += wgt * z2[(size_t)s * 32 + c];
    }
    out[g * 32 + c] = acc / sum + b[c];
}

extern "C" void kernel_launch(void* const* d_in, const int* in_sizes, int n_in,
                              void* d_out, int out_size, void* d_ws, size_t ws_size,
                              hipStream_t stream) {
    const float* x   = (const float*)d_in[0];
    const int*   ei  = (const int*)d_in[1];
    const float* W1  = (const float*)d_in[2];
    const float* av1 = (const float*)d_in[3];
    const float* bv1 = (const float*)d_in[4];
    const float* b1  = (const float*)d_in[5];
    const float* W2  = (const float*)d_in[6];
    const float* av2 = (const float*)d_in[7];
    const float* bv2 = (const float*)d_in[8];
    const float* b2  = (const float*)d_in[9];
    float* out = (float*)d_out;

    // workspace layout (4-byte units)
    unsigned short* z1 = (unsigned short*)d_ws;            // 12.8M bf16 = 6.4M u32
    unsigned short* h1 = (unsigned short*)((float*)d_ws + 6400000);  // 12.8M bf16
    float* as1 = (float*)d_ws + 12800000;                  // 400,000
    float* ad1 = as1 + 400000;                             // 400,000
    float* z2  = ad1 + 400000;                             // 1,600,000
    float* as2 = z2 + 1600000;                             // 50,000
    float* ad2 = as2 + 50000;                              // 50,000
    short8* W1frag = (short8*)(ad2 + 50000);               // 8192 * 16 B = 32768 u32
    short8* W2frag = W1frag + 8192;                        // 1024 * 16 B = 4096 u32
    int* deg       = (int*)(ad2 + 50000) + 36864;          // 50,000
    int* cursor    = deg + 50000;                          // 50,000
    int* row_start = cursor + 50000;                       // 50,001
    int* csr_src   = row_start + 50001;                    // 850,000

    hipMemsetAsync(deg, 0, (size_t)100000 * 4, stream);    // deg + cursor

    // ---- CSR build (shared by both layers) ----
    hist_k<<<(ETOT + 255) / 256, 256, 0, stream>>>(ei, deg);
    scan_k<<<1, 1024, 0, stream>>>(deg, row_start);
    scatter_k<<<(ETOT + 255) / 256, 256, 0, stream>>>(ei, row_start, cursor, csr_src);

    // ---- layer 1 ----
    wprep_k<<<36, 256, 0, stream>>>(W1, W2, W1frag, W2frag);
    gemm1_mfma_k<<<(NNODES + 63) / 64, 256, 0, stream>>>(x, W1frag, av1, bv1, z1, as1, ad1);
    agg1_csr_k<<<(NNODES + 3) / 4, 256, 0, stream>>>(row_start, csr_src, z1, as1, ad1, b1, h1);

    // ---- layer 2 ----
    gemm2_mfma_k<<<(NNODES + 63) / 64, 256, 0, stream>>>(h1, W2frag, av2, bv2, z2, as2, ad2);
    agg2_csr_k<<<(NNODES + 7) / 8, 256, 0, stream>>>(row_start, csr_src, z2, as2, ad2, b2, out);
}

// Round 6
// 365.121 us; speedup vs baseline: 3.5958x; 1.0026x over previous
//
#include <hip/hip_runtime.h>

#define NNODES 50000
#define NFEAT 256
#define NHID 32
#define NHEADS 8
#define NCLASSES 32
#define NEDGES 800000
#define ETOT (NEDGES + NNODES)   // 850000 with self loops

typedef __attribute__((ext_vector_type(8))) short short8;
typedef __attribute__((ext_vector_type(4))) float f32x4;

__device__ __forceinline__ void get_edge(const int* __restrict__ ei, int e,
                                         int& s, int& d) {
    if (e < NEDGES) { s = ei[e]; d = ei[NEDGES + e]; }
    else            { s = e - NEDGES; d = s; }
}
__device__ __forceinline__ float lrelu(float x) { return x > 0.f ? x : 0.2f * x; }
__device__ __forceinline__ unsigned short f2bf(float f) {   // RNE
    unsigned u = __float_as_uint(f);
    unsigned r = u + 0x7fffu + ((u >> 16) & 1u);
    return (unsigned short)(r >> 16);
}
__device__ __forceinline__ float bflo(unsigned u) { return __uint_as_float(u << 16); }
__device__ __forceinline__ float bfhi(unsigned u) { return __uint_as_float(u & 0xffff0000u); }

// ---------- weight prep: fragment-ordered bf16 B-operands ----------
__global__ void wprep_k(const float* __restrict__ W1, const float* __restrict__ W2,
                        short8* __restrict__ W1frag, short8* __restrict__ W2frag) {
    int idx = blockIdx.x * 256 + threadIdx.x;
    if (idx < 8192) {
        int kc = idx >> 10, r = idx & 1023;
        int nt = r >> 6, lane = r & 63;
        int l16 = lane & 15, quad = lane >> 4;
        int n = nt * 16 + l16, k0 = kc * 32 + quad * 8;
        short8 v;
#pragma unroll
        for (int j = 0; j < 8; ++j) v[j] = (short)f2bf(W1[(k0 + j) * 256 + n]);
        W1frag[idx] = v;
    } else if (idx < 8192 + 1024) {
        int g = idx - 8192;
        int kc = g >> 7, r = g & 127;
        int nt = r >> 6, lane = r & 63;
        int l16 = lane & 15, quad = lane >> 4;
        int n = nt * 16 + l16, k0 = kc * 32 + quad * 8;
        short8 v;
#pragma unroll
        for (int j = 0; j < 8; ++j) v[j] = (short)f2bf(W2[(k0 + j) * 32 + n]);
        W2frag[g] = v;
    }
}

// ---------- GEMM1 (MFMA bf16, LDS-staged B) + fused attn1 epilogue ----------
__global__ __launch_bounds__(256) void gemm1_mfma_k(
        const float* __restrict__ x, const short8* __restrict__ Wfrag,
        const float* __restrict__ av, const float* __restrict__ bv,
        unsigned short* __restrict__ z1, float* __restrict__ as_, float* __restrict__ ad_) {
    __shared__ short8 wlds[1024];    // 16 KB: one kc-slice, fragment-ordered
    int t = threadIdx.x;
    int w = t >> 6, lane = t & 63;
    int quad = lane >> 4, l16 = lane & 15;
    int mA = blockIdx.x * 64 + w * 16 + l16;
    int mAl = min(mA, NNODES - 1);

    f32x4 acc[16];
#pragma unroll
    for (int nt = 0; nt < 16; ++nt) acc[nt] = (f32x4){0.f, 0.f, 0.f, 0.f};

    short8 pf[4];
#pragma unroll
    for (int j = 0; j < 4; ++j) pf[j] = Wfrag[j * 256 + t];   // kc=0 slice

    for (int kc = 0; kc < 8; ++kc) {
        __syncthreads();
#pragma unroll
        for (int j = 0; j < 4; ++j) wlds[j * 256 + t] = pf[j];
        __syncthreads();
        if (kc < 7) {
#pragma unroll
            for (int j = 0; j < 4; ++j) pf[j] = Wfrag[(kc + 1) * 1024 + j * 256 + t];
        }
        int k0 = kc * 32 + quad * 8;
        const float4* xp = (const float4*)(x + (size_t)mAl * 256 + k0);
        float4 a0 = xp[0], a1 = xp[1];
        short8 af;
        af[0] = (short)f2bf(a0.x); af[1] = (short)f2bf(a0.y);
        af[2] = (short)f2bf(a0.z); af[3] = (short)f2bf(a0.w);
        af[4] = (short)f2bf(a1.x); af[5] = (short)f2bf(a1.y);
        af[6] = (short)f2bf(a1.z); af[7] = (short)f2bf(a1.w);
#pragma unroll
        for (int nt = 0; nt < 16; ++nt) {
            short8 bf8 = wlds[nt * 64 + lane];
            acc[nt] = __builtin_amdgcn_mfma_f32_16x16x32_bf16(af, bf8, acc[nt], 0, 0, 0);
        }
    }
    int mrow0 = blockIdx.x * 64 + w * 16 + quad * 4;
#pragma unroll
    for (int nt = 0; nt < 16; ++nt) {
        int n = nt * 16 + l16;
#pragma unroll
        for (int r = 0; r < 4; ++r) {
            int mr = mrow0 + r;
            if (mr < NNODES) z1[(size_t)mr * 256 + n] = f2bf(acc[nt][r]);
        }
    }
#pragma unroll
    for (int h = 0; h < 8; ++h) {
        float av0 = av[(2 * h) * 16 + l16], av1v = av[(2 * h + 1) * 16 + l16];
        float bv0 = bv[(2 * h) * 16 + l16], bv1v = bv[(2 * h + 1) * 16 + l16];
#pragma unroll
        for (int r = 0; r < 4; ++r) {
            float pa = acc[2 * h][r] * av0 + acc[2 * h + 1][r] * av1v;
            float pb = acc[2 * h][r] * bv0 + acc[2 * h + 1][r] * bv1v;
#pragma unroll
            for (int off = 1; off < 16; off <<= 1) {
                pa += __shfl_xor(pa, off, 64);
                pb += __shfl_xor(pb, off, 64);
            }
            int mr = mrow0 + r;
            if (l16 == 0 && mr < NNODES) { as_[mr * 8 + h] = pa; ad_[mr * 8 + h] = pb; }
        }
    }
}

// ---------- GEMM2 (MFMA bf16, coalesced fragment B from global/L1) + fused attn2 ----------
__global__ __launch_bounds__(256) void gemm2_mfma_k(
        const unsigned short* __restrict__ h1, const short8* __restrict__ Wfrag,
        const float* __restrict__ av, const float* __restrict__ bv,
        float* __restrict__ z2, float* __restrict__ as_, float* __restrict__ ad_) {
    int w = threadIdx.x >> 6, lane = threadIdx.x & 63;
    int quad = lane >> 4, l16 = lane & 15;
    int mA = blockIdx.x * 64 + w * 16 + l16;
    int mAl = min(mA, NNODES - 1);

    f32x4 acc[2];
    acc[0] = (f32x4){0.f, 0.f, 0.f, 0.f};
    acc[1] = (f32x4){0.f, 0.f, 0.f, 0.f};
    for (int kc = 0; kc < 8; ++kc) {
        int k0 = kc * 32 + quad * 8;
        short8 af = *(const short8*)(h1 + (size_t)mAl * 256 + k0);
#pragma unroll
        for (int nt = 0; nt < 2; ++nt) {
            short8 bf8 = Wfrag[kc * 128 + nt * 64 + lane];
            acc[nt] = __builtin_amdgcn_mfma_f32_16x16x32_bf16(af, bf8, acc[nt], 0, 0, 0);
        }
    }
    int mrow0 = blockIdx.x * 64 + w * 16 + quad * 4;
    float av0 = av[l16], av1v = av[16 + l16];
    float bv0 = bv[l16], bv1v = bv[16 + l16];
#pragma unroll
    for (int r = 0; r < 4; ++r) {
        int mr = mrow0 + r;
        float pa = acc[0][r] * av0 + acc[1][r] * av1v;
        float pb = acc[0][r] * bv0 + acc[1][r] * bv1v;
#pragma unroll
        for (int off = 1; off < 16; off <<= 1) {
            pa += __shfl_xor(pa, off, 64);
            pb += __shfl_xor(pb, off, 64);
        }
        if (mr < NNODES) {
            z2[(size_t)mr * 32 + l16] = acc[0][r];
            z2[(size_t)mr * 32 + 16 + l16] = acc[1][r];
            if (l16 == 0) { as_[mr] = pa; ad_[mr] = pb; }
        }
    }
}

// ---------- CSR build ----------
__global__ void hist_k(const int* __restrict__ ei, int* __restrict__ deg) {
    int e = blockIdx.x * blockDim.x + threadIdx.x;
    if (e >= ETOT) return;
    int s, d;
    get_edge(ei, e, s, d);
    atomicAdd(&deg[d], 1);
}

__global__ void scan_k(const int* __restrict__ deg, int* __restrict__ row_start) {
    __shared__ int wsum[16];
    __shared__ int carry;
    int t = threadIdx.x;
    int lane = t & 63, wid = t >> 6;
    if (t == 0) carry = 0;
    __syncthreads();
    for (int base = 0; base < NNODES; base += 1024) {
        int idx = base + t;
        int v = (idx < NNODES) ? deg[idx] : 0;
        int inc = v;
#pragma unroll
        for (int off = 1; off < 64; off <<= 1) {
            int u = __shfl_up(inc, off, 64);
            if (lane >= off) inc += u;
        }
        if (lane == 63) wsum[wid] = inc;
        __syncthreads();
        if (wid == 0 && lane < 16) {
            int wv = wsum[lane];
#pragma unroll
            for (int off = 1; off < 16; off <<= 1) {
                int u = __shfl_up(wv, off, 64);
                if (lane >= off) wv += u;
            }
            wsum[lane] = wv;
        }
        __syncthreads();
        int woff = (wid == 0) ? 0 : wsum[wid - 1];
        int excl = carry + woff + inc - v;
        if (idx < NNODES) row_start[idx] = excl;
        __syncthreads();
        if (t == 0) carry += wsum[15];
        __syncthreads();
    }
    if (t == 0) row_start[NNODES] = carry;
}

__global__ void scatter_k(const int* __restrict__ ei, const int* __restrict__ row_start,
                          int* __restrict__ cursor, int* __restrict__ csr_src) {
    int e = blockIdx.x * blockDim.x + threadIdx.x;
    if (e >= ETOT) return;
    int s, d;
    get_edge(ei, e, s, d);
    int pos = atomicAdd(&cursor[d], 1);
    csr_src[row_start[d] + pos] = s;
}

// ---------- fused layer-1 aggregation: one wave per dst, shuffle-deduped weights ----------
// lane owns 4 channels c0=lane*4, head h=lane>>3. Per 8-edge batch, lane computes
// the weight for (edge=lane&7, head=lane>>3); w/s broadcast via shuffles.
__global__ void agg1_csr_k(const int* __restrict__ row_start, const int* __restrict__ csr_src,
                           const unsigned short* __restrict__ z, const float* __restrict__ as_,
                           const float* __restrict__ ad_, const float* __restrict__ b,
                           unsigned short* __restrict__ h1) {
    int wv = threadIdx.x >> 6, lane = threadIdx.x & 63;
    int d = blockIdx.x * 4 + wv;
    int h = lane >> 3;
    int c0 = lane * 4;
    int e8 = lane & 7;
    float adh = ad_[d * 8 + h];
    int beg = row_start[d], end = row_start[d + 1];
    float sum = 0.f, a0 = 0.f, a1 = 0.f, a2 = 0.f, a3 = 0.f;
    int i = beg;
    for (; i + 8 <= end; i += 8) {
        int sv = csr_src[i + e8];
        float myw = __expf(lrelu(as_[sv * 8 + h] + adh));
        int se[8];
        float we[8];
#pragma unroll
        for (int e = 0; e < 8; ++e) {
            se[e] = __shfl(sv, e, 64);                 // edge e's src (lane e)
            we[e] = __shfl(myw, (lane & 56) | e, 64);  // w[e][my head]
        }
        uint2 q[8];
#pragma unroll
        for (int e = 0; e < 8; ++e)
            q[e] = *(const uint2*)(z + (size_t)se[e] * 256 + c0);
#pragma unroll
        for (int e = 0; e < 8; ++e) {
            float wgt = we[e];
            sum += wgt;
            a0 += wgt * bflo(q[e].x);
            a1 += wgt * bfhi(q[e].x);
            a2 += wgt * bflo(q[e].y);
            a3 += wgt * bfhi(q[e].y);
        }
    }
    for (; i < end; ++i) {
        int s = csr_src[i];
        float wgt = __expf(lrelu(as_[s * 8 + h] + adh));
        uint2 zz = *(const uint2*)(z + (size_t)s * 256 + c0);
        sum += wgt;
        a0 += wgt * bflo(zz.x);
        a1 += wgt * bfhi(zz.x);
        a2 += wgt * bflo(zz.y);
        a3 += wgt * bfhi(zz.y);
    }
    float inv = 1.f / sum;
    float o0 = a0 * inv + b[c0 + 0];
    float o1 = a1 * inv + b[c0 + 1];
    float o2 = a2 * inv + b[c0 + 2];
    float o3 = a3 * inv + b[c0 + 3];
    o0 = o0 > 0.f ? o0 : expm1f(o0);
    o1 = o1 > 0.f ? o1 : expm1f(o1);
    o2 = o2 > 0.f ? o2 : expm1f(o2);
    o3 = o3 > 0.f ? o3 : expm1f(o3);
    uint2 pk;
    pk.x = (unsigned)f2bf(o0) | ((unsigned)f2bf(o1) << 16);
    pk.y = (unsigned)f2bf(o2) | ((unsigned)f2bf(o3) << 16);
    *(uint2*)(h1 + (size_t)d * 256 + c0) = pk;
}

// ---------- fused layer-2 aggregation + bias: 2 dsts/wave, width-32 shuffles ----------
__global__ void agg2_csr_k(const int* __restrict__ row_start, const int* __restrict__ csr_src,
                           const float* __restrict__ z2, const float* __restrict__ as_,
                           const float* __restrict__ ad_, const float* __restrict__ b,
                           float* __restrict__ out) {
    int g = blockIdx.x * 8 + (threadIdx.x >> 5);
    int c = threadIdx.x & 31;
    if (g >= NNODES) return;
    int beg = row_start[g], end = row_start[g + 1];
    float adn = ad_[g];
    int e8 = c & 7;
    float sum = 0.f, acc = 0.f;
    int i = beg;
    for (; i + 8 <= end; i += 8) {
        int sv = csr_src[i + e8];
        float myw = __expf(lrelu(as_[sv] + adn));
        int se[8];
        float we[8];
#pragma unroll
        for (int e = 0; e < 8; ++e) {
            se[e] = __shfl(sv, e, 32);
            we[e] = __shfl(myw, e, 32);
        }
        float v[8];
#pragma unroll
        for (int e = 0; e < 8; ++e) v[e] = z2[(size_t)se[e] * 32 + c];
#pragma unroll
        for (int e = 0; e < 8; ++e) { sum += we[e]; acc += we[e] * v[e]; }
    }
    for (; i < end; ++i) {
        int s = csr_src[i];
        float wgt = __expf(lrelu(as_[s] + adn));
        sum += wgt;
        acc += wgt * z2[(size_t)s * 32 + c];
    }
    out[g * 32 + c] = acc / sum + b[c];
}

extern "C" void kernel_launch(void* const* d_in, const int* in_sizes, int n_in,
                              void* d_out, int out_size, void* d_ws, size_t ws_size,
                              hipStream_t stream) {
    const float* x   = (const float*)d_in[0];
    const int*   ei  = (const int*)d_in[1];
    const float* W1  = (const float*)d_in[2];
    const float* av1 = (const float*)d_in[3];
    const float* bv1 = (const float*)d_in[4];
    const float* b1  = (const float*)d_in[5];
    const float* W2  = (const float*)d_in[6];
    const float* av2 = (const float*)d_in[7];
    const float* bv2 = (const float*)d_in[8];
    const float* b2  = (const float*)d_in[9];
    float* out = (float*)d_out;

    // workspace layout (4-byte units)
    unsigned short* z1 = (unsigned short*)d_ws;            // 12.8M bf16 = 6.4M u32
    unsigned short* h1 = (unsigned short*)((float*)d_ws + 6400000);  // 12.8M bf16
    float* as1 = (float*)d_ws + 12800000;                  // 400,000
    float* ad1 = as1 + 400000;                             // 400,000
    float* z2  = ad1 + 400000;                             // 1,600,000
    float* as2 = z2 + 1600000;                             // 50,000
    float* ad2 = as2 + 50000;                              // 50,000
    short8* W1frag = (short8*)(ad2 + 50000);               // 8192 * 16 B
    short8* W2frag = W1frag + 8192;                        // 1024 * 16 B
    int* deg       = (int*)(ad2 + 50000) + 36864;          // 50,000
    int* cursor    = deg + 50000;                          // 50,000
    int* row_start = cursor + 50000;                       // 50,001
    int* csr_src   = row_start + 50001;                    // 850,000

    hipMemsetAsync(deg, 0, (size_t)100000 * 4, stream);    // deg + cursor

    // ---- CSR build (shared by both layers) ----
    hist_k<<<(ETOT + 255) / 256, 256, 0, stream>>>(ei, deg);
    scan_k<<<1, 1024, 0, stream>>>(deg, row_start);
    scatter_k<<<(ETOT + 255) / 256, 256, 0, stream>>>(ei, row_start, cursor, csr_src);

    // ---- layer 1 ----
    wprep_k<<<36, 256, 0, stream>>>(W1, W2, W1frag, W2frag);
    gemm1_mfma_k<<<(NNODES + 63) / 64, 256, 0, stream>>>(x, W1frag, av1, bv1, z1, as1, ad1);
    agg1_csr_k<<<(NNODES + 3) / 4, 256, 0, stream>>>(row_start, csr_src, z1, as1, ad1, b1, h1);

    // ---- layer 2 ----
    gemm2_mfma_k<<<(NNODES + 63) / 64, 256, 0, stream>>>(h1, W2frag, av2, bv2, z2, as2, ad2);
    agg2_csr_k<<<(NNODES + 7) / 8, 256, 0, stream>>>(row_start, csr_src, z2, as2, ad2, b2, out);
}

// Round 7
// 339.170 us; speedup vs baseline: 3.8710x; 1.0765x over previous
//
#include <hip/hip_runtime.h>

#define NNODES 50000
#define NFEAT 256
#define NHID 32
#define NHEADS 8
#define NCLASSES 32
#define NEDGES 800000
#define ETOT (NEDGES + NNODES)   // 850000 with self loops
#define NSCAN_BLK 196            // ceil(50000/256)

typedef __attribute__((ext_vector_type(8))) short short8;
typedef __attribute__((ext_vector_type(4))) float f32x4;

__device__ __forceinline__ void get_edge(const int* __restrict__ ei, int e,
                                         int& s, int& d) {
    if (e < NEDGES) { s = ei[e]; d = ei[NEDGES + e]; }
    else            { s = e - NEDGES; d = s; }
}
__device__ __forceinline__ float lrelu(float x) { return x > 0.f ? x : 0.2f * x; }
__device__ __forceinline__ unsigned short f2bf(float f) {   // RNE
    unsigned u = __float_as_uint(f);
    unsigned r = u + 0x7fffu + ((u >> 16) & 1u);
    return (unsigned short)(r >> 16);
}
__device__ __forceinline__ float bflo(unsigned u) { return __uint_as_float(u << 16); }
__device__ __forceinline__ float bfhi(unsigned u) { return __uint_as_float(u & 0xffff0000u); }

// ---------- fused: weight prep (blocks 0..35) + degree histogram (rest) ----------
__global__ void wprep_hist_k(const float* __restrict__ W1, const float* __restrict__ W2,
                             short8* __restrict__ W1frag, short8* __restrict__ W2frag,
                             const int* __restrict__ ei, int* __restrict__ deg) {
    if (blockIdx.x < 36) {
        int idx = blockIdx.x * 256 + threadIdx.x;
        if (idx < 8192) {
            int kc = idx >> 10, r = idx & 1023;
            int nt = r >> 6, lane = r & 63;
            int l16 = lane & 15, quad = lane >> 4;
            int n = nt * 16 + l16, k0 = kc * 32 + quad * 8;
            short8 v;
#pragma unroll
            for (int j = 0; j < 8; ++j) v[j] = (short)f2bf(W1[(k0 + j) * 256 + n]);
            W1frag[idx] = v;
        } else if (idx < 8192 + 1024) {
            int g = idx - 8192;
            int kc = g >> 7, r = g & 127;
            int nt = r >> 6, lane = r & 63;
            int l16 = lane & 15, quad = lane >> 4;
            int n = nt * 16 + l16, k0 = kc * 32 + quad * 8;
            short8 v;
#pragma unroll
            for (int j = 0; j < 8; ++j) v[j] = (short)f2bf(W2[(k0 + j) * 32 + n]);
            W2frag[g] = v;
        }
    } else {
        int e = (blockIdx.x - 36) * 256 + threadIdx.x;
        if (e >= ETOT) return;
        int s, d;
        get_edge(ei, e, s, d);
        atomicAdd(&deg[d], 1);
    }
}

// ---------- parallel scan, phase 1: per-block exclusive scan + block sums ----------
__global__ void scan_part_k(const int* __restrict__ deg, int* __restrict__ row_local,
                            int* __restrict__ bsum) {
    __shared__ int ws[4];
    int t = threadIdx.x, lane = t & 63, wid = t >> 6;
    int idx = blockIdx.x * 256 + t;
    int v = (idx < NNODES) ? deg[idx] : 0;
    int inc = v;
#pragma unroll
    for (int off = 1; off < 64; off <<= 1) {
        int u = __shfl_up(inc, off, 64);
        if (lane >= off) inc += u;
    }
    if (lane == 63) ws[wid] = inc;
    __syncthreads();
    int woff = 0;
#pragma unroll
    for (int j = 0; j < 4; ++j) woff += (j < wid) ? ws[j] : 0;
    if (idx < NNODES) row_local[idx] = woff + inc - v;
    if (t == 255) bsum[blockIdx.x] = woff + inc;
}

// ---------- scan phase 2: exclusive scan of 196 block sums ----------
__global__ void scan_bsum_k(const int* __restrict__ bsum, int* __restrict__ boff) {
    __shared__ int ws[4];
    int t = threadIdx.x, lane = t & 63, wid = t >> 6;
    int v = (t < NSCAN_BLK) ? bsum[t] : 0;
    int inc = v;
#pragma unroll
    for (int off = 1; off < 64; off <<= 1) {
        int u = __shfl_up(inc, off, 64);
        if (lane >= off) inc += u;
    }
    if (lane == 63) ws[wid] = inc;
    __syncthreads();
    int woff = 0;
#pragma unroll
    for (int j = 0; j < 4; ++j) woff += (j < wid) ? ws[j] : 0;
    if (t < NSCAN_BLK) boff[t] = woff + inc - v;
}

// ---------- scan phase 3: fixup to final row_start ----------
__global__ void scan_fix_k(const int* __restrict__ row_local, const int* __restrict__ boff,
                           int* __restrict__ row_start) {
    int idx = blockIdx.x * 256 + threadIdx.x;
    if (idx < NNODES) row_start[idx] = row_local[idx] + boff[idx >> 8];
    if (idx == 0) row_start[NNODES] = ETOT;
}

__global__ void scatter_k(const int* __restrict__ ei, const int* __restrict__ row_start,
                          int* __restrict__ cursor, int* __restrict__ csr_src) {
    int e = blockIdx.x * blockDim.x + threadIdx.x;
    if (e >= ETOT) return;
    int s, d;
    get_edge(ei, e, s, d);
    int pos = atomicAdd(&cursor[d], 1);
    csr_src[row_start[d] + pos] = s;
}

// ---------- GEMM1 (MFMA bf16, LDS-staged B) + fused attn1 epilogue ----------
__global__ __launch_bounds__(256) void gemm1_mfma_k(
        const float* __restrict__ x, const short8* __restrict__ Wfrag,
        const float* __restrict__ av, const float* __restrict__ bv,
        unsigned short* __restrict__ z1, float* __restrict__ as_, float* __restrict__ ad_) {
    __shared__ short8 wlds[1024];    // 16 KB: one kc-slice, fragment-ordered
    int t = threadIdx.x;
    int w = t >> 6, lane = t & 63;
    int quad = lane >> 4, l16 = lane & 15;
    int mA = blockIdx.x * 64 + w * 16 + l16;
    int mAl = min(mA, NNODES - 1);

    f32x4 acc[16];
#pragma unroll
    for (int nt = 0; nt < 16; ++nt) acc[nt] = (f32x4){0.f, 0.f, 0.f, 0.f};

    short8 pf[4];
#pragma unroll
    for (int j = 0; j < 4; ++j) pf[j] = Wfrag[j * 256 + t];   // kc=0 slice

    for (int kc = 0; kc < 8; ++kc) {
        __syncthreads();
#pragma unroll
        for (int j = 0; j < 4; ++j) wlds[j * 256 + t] = pf[j];
        __syncthreads();
        if (kc < 7) {
#pragma unroll
            for (int j = 0; j < 4; ++j) pf[j] = Wfrag[(kc + 1) * 1024 + j * 256 + t];
        }
        int k0 = kc * 32 + quad * 8;
        const float4* xp = (const float4*)(x + (size_t)mAl * 256 + k0);
        float4 a0 = xp[0], a1 = xp[1];
        short8 af;
        af[0] = (short)f2bf(a0.x); af[1] = (short)f2bf(a0.y);
        af[2] = (short)f2bf(a0.z); af[3] = (short)f2bf(a0.w);
        af[4] = (short)f2bf(a1.x); af[5] = (short)f2bf(a1.y);
        af[6] = (short)f2bf(a1.z); af[7] = (short)f2bf(a1.w);
#pragma unroll
        for (int nt = 0; nt < 16; ++nt) {
            short8 bf8 = wlds[nt * 64 + lane];
            acc[nt] = __builtin_amdgcn_mfma_f32_16x16x32_bf16(af, bf8, acc[nt], 0, 0, 0);
        }
    }
    int mrow0 = blockIdx.x * 64 + w * 16 + quad * 4;
#pragma unroll
    for (int nt = 0; nt < 16; ++nt) {
        int n = nt * 16 + l16;
#pragma unroll
        for (int r = 0; r < 4; ++r) {
            int mr = mrow0 + r;
            if (mr < NNODES) z1[(size_t)mr * 256 + n] = f2bf(acc[nt][r]);
        }
    }
#pragma unroll
    for (int h = 0; h < 8; ++h) {
        float av0 = av[(2 * h) * 16 + l16], av1v = av[(2 * h + 1) * 16 + l16];
        float bv0 = bv[(2 * h) * 16 + l16], bv1v = bv[(2 * h + 1) * 16 + l16];
#pragma unroll
        for (int r = 0; r < 4; ++r) {
            float pa = acc[2 * h][r] * av0 + acc[2 * h + 1][r] * av1v;
            float pb = acc[2 * h][r] * bv0 + acc[2 * h + 1][r] * bv1v;
#pragma unroll
            for (int off = 1; off < 16; off <<= 1) {
                pa += __shfl_xor(pa, off, 64);
                pb += __shfl_xor(pb, off, 64);
            }
            int mr = mrow0 + r;
            if (l16 == 0 && mr < NNODES) { as_[mr * 8 + h] = pa; ad_[mr * 8 + h] = pb; }
        }
    }
}

// ---------- GEMM2 (MFMA bf16, coalesced fragment B from global/L1) + fused attn2 ----------
__global__ __launch_bounds__(256) void gemm2_mfma_k(
        const unsigned short* __restrict__ h1, const short8* __restrict__ Wfrag,
        const float* __restrict__ av, const float* __restrict__ bv,
        float* __restrict__ z2, float* __restrict__ as_, float* __restrict__ ad_) {
    int w = threadIdx.x >> 6, lane = threadIdx.x & 63;
    int quad = lane >> 4, l16 = lane & 15;
    int mA = blockIdx.x * 64 + w * 16 + l16;
    int mAl = min(mA, NNODES - 1);

    f32x4 acc[2];
    acc[0] = (f32x4){0.f, 0.f, 0.f, 0.f};
    acc[1] = (f32x4){0.f, 0.f, 0.f, 0.f};
    for (int kc = 0; kc < 8; ++kc) {
        int k0 = kc * 32 + quad * 8;
        short8 af = *(const short8*)(h1 + (size_t)mAl * 256 + k0);
#pragma unroll
        for (int nt = 0; nt < 2; ++nt) {
            short8 bf8 = Wfrag[kc * 128 + nt * 64 + lane];
            acc[nt] = __builtin_amdgcn_mfma_f32_16x16x32_bf16(af, bf8, acc[nt], 0, 0, 0);
        }
    }
    int mrow0 = blockIdx.x * 64 + w * 16 + quad * 4;
    float av0 = av[l16], av1v = av[16 + l16];
    float bv0 = bv[l16], bv1v = bv[16 + l16];
#pragma unroll
    for (int r = 0; r < 4; ++r) {
        int mr = mrow0 + r;
        float pa = acc[0][r] * av0 + acc[1][r] * av1v;
        float pb = acc[0][r] * bv0 + acc[1][r] * bv1v;
#pragma unroll
        for (int off = 1; off < 16; off <<= 1) {
            pa += __shfl_xor(pa, off, 64);
            pb += __shfl_xor(pb, off, 64);
        }
        if (mr < NNODES) {
            z2[(size_t)mr * 32 + l16] = acc[0][r];
            z2[(size_t)mr * 32 + 16 + l16] = acc[1][r];
            if (l16 == 0) { as_[mr] = pa; ad_[mr] = pb; }
        }
    }
}

// ---------- fused layer-1 aggregation: one wave per dst, 16-deep, shuffle-deduped ----------
__global__ void agg1_csr_k(const int* __restrict__ row_start, const int* __restrict__ csr_src,
                           const unsigned short* __restrict__ z, const float* __restrict__ as_,
                           const float* __restrict__ ad_, const float* __restrict__ b,
                           unsigned short* __restrict__ h1) {
    int wv = threadIdx.x >> 6, lane = threadIdx.x & 63;
    int d = blockIdx.x * 4 + wv;
    int h = lane >> 3;
    int c0 = lane * 4;
    int e8 = lane & 7;
    float adh = ad_[d * 8 + h];
    int beg = row_start[d], end = row_start[d + 1];
    float sum = 0.f, a0 = 0.f, a1 = 0.f, a2 = 0.f, a3 = 0.f;
    int i = beg;
    for (; i + 16 <= end; i += 16) {
        int sv0 = csr_src[i + e8];
        int sv1 = csr_src[i + 8 + e8];
        float w0 = __expf(lrelu(as_[sv0 * 8 + h] + adh));
        float w1 = __expf(lrelu(as_[sv1 * 8 + h] + adh));
        uint2 q[16];
#pragma unroll
        for (int e = 0; e < 8; ++e) {
            int se = __shfl(sv0, e, 64);
            q[e] = *(const uint2*)(z + (size_t)se * 256 + c0);
        }
#pragma unroll
        for (int e = 0; e < 8; ++e) {
            int se = __shfl(sv1, e, 64);
            q[8 + e] = *(const uint2*)(z + (size_t)se * 256 + c0);
        }
#pragma unroll
        for (int e = 0; e < 8; ++e) {
            float wgt = __shfl(w0, (lane & 56) | e, 64);
            sum += wgt;
            a0 += wgt * bflo(q[e].x);
            a1 += wgt * bfhi(q[e].x);
            a2 += wgt * bflo(q[e].y);
            a3 += wgt * bfhi(q[e].y);
        }
#pragma unroll
        for (int e = 0; e < 8; ++e) {
            float wgt = __shfl(w1, (lane & 56) | e, 64);
            sum += wgt;
            a0 += wgt * bflo(q[8 + e].x);
            a1 += wgt * bfhi(q[8 + e].x);
            a2 += wgt * bflo(q[8 + e].y);
            a3 += wgt * bfhi(q[8 + e].y);
        }
    }
    for (; i + 8 <= end; i += 8) {
        int sv = csr_src[i + e8];
        float myw = __expf(lrelu(as_[sv * 8 + h] + adh));
        uint2 q[8];
#pragma unroll
        for (int e = 0; e < 8; ++e) {
            int se = __shfl(sv, e, 64);
            q[e] = *(const uint2*)(z + (size_t)se * 256 + c0);
        }
#pragma unroll
        for (int e = 0; e < 8; ++e) {
            float wgt = __shfl(myw, (lane & 56) | e, 64);
            sum += wgt;
            a0 += wgt * bflo(q[e].x);
            a1 += wgt * bfhi(q[e].x);
            a2 += wgt * bflo(q[e].y);
            a3 += wgt * bfhi(q[e].y);
        }
    }
    for (; i < end; ++i) {
        int s = csr_src[i];
        float wgt = __expf(lrelu(as_[s * 8 + h] + adh));
        uint2 zz = *(const uint2*)(z + (size_t)s * 256 + c0);
        sum += wgt;
        a0 += wgt * bflo(zz.x);
        a1 += wgt * bfhi(zz.x);
        a2 += wgt * bflo(zz.y);
        a3 += wgt * bfhi(zz.y);
    }
    float inv = 1.f / sum;
    float o0 = a0 * inv + b[c0 + 0];
    float o1 = a1 * inv + b[c0 + 1];
    float o2 = a2 * inv + b[c0 + 2];
    float o3 = a3 * inv + b[c0 + 3];
    o0 = o0 > 0.f ? o0 : expm1f(o0);
    o1 = o1 > 0.f ? o1 : expm1f(o1);
    o2 = o2 > 0.f ? o2 : expm1f(o2);
    o3 = o3 > 0.f ? o3 : expm1f(o3);
    uint2 pk;
    pk.x = (unsigned)f2bf(o0) | ((unsigned)f2bf(o1) << 16);
    pk.y = (unsigned)f2bf(o2) | ((unsigned)f2bf(o3) << 16);
    *(uint2*)(h1 + (size_t)d * 256 + c0) = pk;
}

// ---------- fused layer-2 aggregation + bias: 2 dsts/wave, width-32 shuffles, 16-deep ----------
__global__ void agg2_csr_k(const int* __restrict__ row_start, const int* __restrict__ csr_src,
                           const float* __restrict__ z2, const float* __restrict__ as_,
                           const float* __restrict__ ad_, const float* __restrict__ b,
                           float* __restrict__ out) {
    int g = blockIdx.x * 8 + (threadIdx.x >> 5);
    int c = threadIdx.x & 31;
    if (g >= NNODES) return;
    int beg = row_start[g], end = row_start[g + 1];
    float adn = ad_[g];
    int e8 = c & 7;
    float sum = 0.f, acc = 0.f;
    int i = beg;
    for (; i + 16 <= end; i += 16) {
        int sv0 = csr_src[i + e8];
        int sv1 = csr_src[i + 8 + e8];
        float w0 = __expf(lrelu(as_[sv0] + adn));
        float w1 = __expf(lrelu(as_[sv1] + adn));
        float v[16];
#pragma unroll
        for (int e = 0; e < 8; ++e) {
            int se = __shfl(sv0, e, 32);
            v[e] = z2[(size_t)se * 32 + c];
        }
#pragma unroll
        for (int e = 0; e < 8; ++e) {
            int se = __shfl(sv1, e, 32);
            v[8 + e] = z2[(size_t)se * 32 + c];
        }
#pragma unroll
        for (int e = 0; e < 8; ++e) {
            float wgt = __shfl(w0, e, 32);
            sum += wgt; acc += wgt * v[e];
        }
#pragma unroll
        for (int e = 0; e < 8; ++e) {
            float wgt = __shfl(w1, e, 32);
            sum += wgt; acc += wgt * v[8 + e];
        }
    }
    for (; i + 8 <= end; i += 8) {
        int sv = csr_src[i + e8];
        float myw = __expf(lrelu(as_[sv] + adn));
        float v[8];
#pragma unroll
        for (int e = 0; e < 8; ++e) {
            int se = __shfl(sv, e, 32);
            v[e] = z2[(size_t)se * 32 + c];
        }
#pragma unroll
        for (int e = 0; e < 8; ++e) {
            float wgt = __shfl(myw, e, 32);
            sum += wgt; acc += wgt * v[e];
        }
    }
    for (; i < end; ++i) {
        int s = csr_src[i];
        float wgt = __expf(lrelu(as_[s] + adn));
        sum += wgt;
        acc += wgt * z2[(size_t)s * 32 + c];
    }
    out[g * 32 + c] = acc / sum + b[c];
}

extern "C" void kernel_launch(void* const* d_in, const int* in_sizes, int n_in,
                              void* d_out, int out_size, void* d_ws, size_t ws_size,
                              hipStream_t stream) {
    const float* x   = (const float*)d_in[0];
    const int*   ei  = (const int*)d_in[1];
    const float* W1  = (const float*)d_in[2];
    const float* av1 = (const float*)d_in[3];
    const float* bv1 = (const float*)d_in[4];
    const float* b1  = (const float*)d_in[5];
    const float* W2  = (const float*)d_in[6];
    const float* av2 = (const float*)d_in[7];
    const float* bv2 = (const float*)d_in[8];
    const float* b2  = (const float*)d_in[9];
    float* out = (float*)d_out;

    // workspace layout (4-byte units)
    unsigned short* z1 = (unsigned short*)d_ws;            // 12.8M bf16 = 6.4M u32
    unsigned short* h1 = (unsigned short*)((float*)d_ws + 6400000);  // 12.8M bf16
    float* as1 = (float*)d_ws + 12800000;                  // 400,000
    float* ad1 = as1 + 400000;                             // 400,000
    float* z2  = ad1 + 400000;                             // 1,600,000
    float* as2 = z2 + 1600000;                             // 50,000
    float* ad2 = as2 + 50000;                              // 50,000
    short8* W1frag = (short8*)(ad2 + 50000);               // 8192 * 16 B
    short8* W2frag = W1frag + 8192;                        // 1024 * 16 B
    int* deg       = (int*)(ad2 + 50000) + 36864;          // 50,000
    int* cursor    = deg + 50000;                          // 50,000
    int* row_start = cursor + 50000;                       // 50,001
    int* csr_src   = row_start + 50001;                    // 850,000
    int* row_local = csr_src + 850000;                     // 50,000
    int* bsum      = row_local + 50000;                    // 256
    int* boff      = bsum + 256;                           // 256

    hipMemsetAsync(deg, 0, (size_t)100000 * 4, stream);    // deg + cursor

    // ---- CSR build + weight prep ----
    wprep_hist_k<<<36 + (ETOT + 255) / 256, 256, 0, stream>>>(W1, W2, W1frag, W2frag, ei, deg);
    scan_part_k<<<NSCAN_BLK, 256, 0, stream>>>(deg, row_local, bsum);
    scan_bsum_k<<<1, 256, 0, stream>>>(bsum, boff);
    scan_fix_k<<<NSCAN_BLK, 256, 0, stream>>>(row_local, boff, row_start);
    scatter_k<<<(ETOT + 255) / 256, 256, 0, stream>>>(ei, row_start, cursor, csr_src);

    // ---- layer 1 ----
    gemm1_mfma_k<<<(NNODES + 63) / 64, 256, 0, stream>>>(x, W1frag, av1, bv1, z1, as1, ad1);
    agg1_csr_k<<<(NNODES + 3) / 4, 256, 0, stream>>>(row_start, csr_src, z1, as1, ad1, b1, h1);

    // ---- layer 2 ----
    gemm2_mfma_k<<<(NNODES + 63) / 64, 256, 0, stream>>>(h1, W2frag, av2, bv2, z2, as2, ad2);
    agg2_csr_k<<<(NNODES + 7) / 8, 256, 0, stream>>>(row_start, csr_src, z2, as2, ad2, b2, out);
}

// Round 8
// 295.968 us; speedup vs baseline: 4.4360x; 1.1460x over previous
//
#include <hip/hip_runtime.h>

#define NNODES 50000
#define NFEAT 256
#define NHID 32
#define NHEADS 8
#define NCLASSES 32
#define NEDGES 800000
#define ETOT (NEDGES + NNODES)   // 850000 with self loops
#define NSCAN_BLK 196            // ceil(50000/256)
#define GEMM1_BLKS 782           // ceil(50000/64)
#define SCAT_BLKS 3321           // ceil(850000/256)

typedef __attribute__((ext_vector_type(8))) short short8;
typedef __attribute__((ext_vector_type(4))) float f32x4;

__device__ __forceinline__ void get_edge(const int* __restrict__ ei, int e,
                                         int& s, int& d) {
    if (e < NEDGES) { s = ei[e]; d = ei[NEDGES + e]; }
    else            { s = e - NEDGES; d = s; }
}
__device__ __forceinline__ float lrelu(float x) { return x > 0.f ? x : 0.2f * x; }
__device__ __forceinline__ unsigned short f2bf(float f) {   // RNE
    unsigned u = __float_as_uint(f);
    unsigned r = u + 0x7fffu + ((u >> 16) & 1u);
    return (unsigned short)(r >> 16);
}
__device__ __forceinline__ float bflo(unsigned u) { return __uint_as_float(u << 16); }
__device__ __forceinline__ float bfhi(unsigned u) { return __uint_as_float(u & 0xffff0000u); }

// ---------- fused: weight prep (blocks 0..35) + degree histogram (rest) ----------
__global__ void wprep_hist_k(const float* __restrict__ W1, const float* __restrict__ W2,
                             short8* __restrict__ W1frag, short8* __restrict__ W2frag,
                             const int* __restrict__ ei, int* __restrict__ deg) {
    if (blockIdx.x < 36) {
        int idx = blockIdx.x * 256 + threadIdx.x;
        if (idx < 8192) {
            int kc = idx >> 10, r = idx & 1023;
            int nt = r >> 6, lane = r & 63;
            int l16 = lane & 15, quad = lane >> 4;
            int n = nt * 16 + l16, k0 = kc * 32 + quad * 8;
            short8 v;
#pragma unroll
            for (int j = 0; j < 8; ++j) v[j] = (short)f2bf(W1[(k0 + j) * 256 + n]);
            W1frag[idx] = v;
        } else if (idx < 8192 + 1024) {
            int g = idx - 8192;
            int kc = g >> 7, r = g & 127;
            int nt = r >> 6, lane = r & 63;
            int l16 = lane & 15, quad = lane >> 4;
            int n = nt * 16 + l16, k0 = kc * 32 + quad * 8;
            short8 v;
#pragma unroll
            for (int j = 0; j < 8; ++j) v[j] = (short)f2bf(W2[(k0 + j) * 32 + n]);
            W2frag[g] = v;
        }
    } else {
        int e = (blockIdx.x - 36) * 256 + threadIdx.x;
        if (e >= ETOT) return;
        int s, d;
        get_edge(ei, e, s, d);
        atomicAdd(&deg[d], 1);
    }
}

// ---------- parallel scan, phase 1: per-block exclusive scan + block sums ----------
__global__ void scan_part_k(const int* __restrict__ deg, int* __restrict__ row_local,
                            int* __restrict__ bsum) {
    __shared__ int ws[4];
    int t = threadIdx.x, lane = t & 63, wid = t >> 6;
    int idx = blockIdx.x * 256 + t;
    int v = (idx < NNODES) ? deg[idx] : 0;
    int inc = v;
#pragma unroll
    for (int off = 1; off < 64; off <<= 1) {
        int u = __shfl_up(inc, off, 64);
        if (lane >= off) inc += u;
    }
    if (lane == 63) ws[wid] = inc;
    __syncthreads();
    int woff = 0;
#pragma unroll
    for (int j = 0; j < 4; ++j) woff += (j < wid) ? ws[j] : 0;
    if (idx < NNODES) row_local[idx] = woff + inc - v;
    if (t == 255) bsum[blockIdx.x] = woff + inc;
}

// ---------- scan phase 2+3 merged: each block scans bsum, picks own offset, fixes up ----------
__global__ void scan_fix_k(const int* __restrict__ row_local, const int* __restrict__ bsum,
                           int* __restrict__ row_start) {
    __shared__ int ws[4];
    __shared__ int sboff;
    int t = threadIdx.x, lane = t & 63, wid = t >> 6;
    int v = (t < NSCAN_BLK) ? bsum[t] : 0;
    int inc = v;
#pragma unroll
    for (int off = 1; off < 64; off <<= 1) {
        int u = __shfl_up(inc, off, 64);
        if (lane >= off) inc += u;
    }
    if (lane == 63) ws[wid] = inc;
    __syncthreads();
    int woff = 0;
#pragma unroll
    for (int j = 0; j < 4; ++j) woff += (j < wid) ? ws[j] : 0;
    if (t == blockIdx.x) sboff = woff + inc - v;   // exclusive prefix of my block
    __syncthreads();
    int idx = blockIdx.x * 256 + t;
    if (idx < NNODES) row_start[idx] = row_local[idx] + sboff;
    if (idx == 0) row_start[NNODES] = ETOT;
}

// ---------- fused GEMM1 (MFMA bf16, LDS-staged B) + attn1 epilogue + CSR scatter ----------
__global__ __launch_bounds__(256) void gemm1_scatter_k(
        const float* __restrict__ x, const short8* __restrict__ Wfrag,
        const float* __restrict__ av, const float* __restrict__ bv,
        unsigned short* __restrict__ z1, float* __restrict__ as_, float* __restrict__ ad_,
        const int* __restrict__ ei, const int* __restrict__ row_start,
        int* __restrict__ cursor, int* __restrict__ csr_src) {
    __shared__ short8 wlds[1024];    // 16 KB: one kc-slice, fragment-ordered
    if (blockIdx.x >= GEMM1_BLKS) {
        int e = (blockIdx.x - GEMM1_BLKS) * 256 + threadIdx.x;
        if (e >= ETOT) return;
        int s, d;
        get_edge(ei, e, s, d);
        int pos = atomicAdd(&cursor[d], 1);
        csr_src[row_start[d] + pos] = s;
        return;
    }
    int t = threadIdx.x;
    int w = t >> 6, lane = t & 63;
    int quad = lane >> 4, l16 = lane & 15;
    int mA = blockIdx.x * 64 + w * 16 + l16;
    int mAl = min(mA, NNODES - 1);

    f32x4 acc[16];
#pragma unroll
    for (int nt = 0; nt < 16; ++nt) acc[nt] = (f32x4){0.f, 0.f, 0.f, 0.f};

    short8 pf[4];
#pragma unroll
    for (int j = 0; j < 4; ++j) pf[j] = Wfrag[j * 256 + t];   // kc=0 slice

    for (int kc = 0; kc < 8; ++kc) {
        __syncthreads();
#pragma unroll
        for (int j = 0; j < 4; ++j) wlds[j * 256 + t] = pf[j];
        __syncthreads();
        if (kc < 7) {
#pragma unroll
            for (int j = 0; j < 4; ++j) pf[j] = Wfrag[(kc + 1) * 1024 + j * 256 + t];
        }
        int k0 = kc * 32 + quad * 8;
        const float4* xp = (const float4*)(x + (size_t)mAl * 256 + k0);
        float4 a0 = xp[0], a1 = xp[1];
        short8 af;
        af[0] = (short)f2bf(a0.x); af[1] = (short)f2bf(a0.y);
        af[2] = (short)f2bf(a0.z); af[3] = (short)f2bf(a0.w);
        af[4] = (short)f2bf(a1.x); af[5] = (short)f2bf(a1.y);
        af[6] = (short)f2bf(a1.z); af[7] = (short)f2bf(a1.w);
#pragma unroll
        for (int nt = 0; nt < 16; ++nt) {
            short8 bf8 = wlds[nt * 64 + lane];
            acc[nt] = __builtin_amdgcn_mfma_f32_16x16x32_bf16(af, bf8, acc[nt], 0, 0, 0);
        }
    }
    int mrow0 = blockIdx.x * 64 + w * 16 + quad * 4;
#pragma unroll
    for (int nt = 0; nt < 16; ++nt) {
        int n = nt * 16 + l16;
#pragma unroll
        for (int r = 0; r < 4; ++r) {
            int mr = mrow0 + r;
            if (mr < NNODES) z1[(size_t)mr * 256 + n] = f2bf(acc[nt][r]);
        }
    }
#pragma unroll
    for (int h = 0; h < 8; ++h) {
        float av0 = av[(2 * h) * 16 + l16], av1v = av[(2 * h + 1) * 16 + l16];
        float bv0 = bv[(2 * h) * 16 + l16], bv1v = bv[(2 * h + 1) * 16 + l16];
#pragma unroll
        for (int r = 0; r < 4; ++r) {
            float pa = acc[2 * h][r] * av0 + acc[2 * h + 1][r] * av1v;
            float pb = acc[2 * h][r] * bv0 + acc[2 * h + 1][r] * bv1v;
#pragma unroll
            for (int off = 1; off < 16; off <<= 1) {
                pa += __shfl_xor(pa, off, 64);
                pb += __shfl_xor(pb, off, 64);
            }
            int mr = mrow0 + r;
            if (l16 == 0 && mr < NNODES) { as_[mr * 8 + h] = pa; ad_[mr * 8 + h] = pb; }
        }
    }
}

// ---------- GEMM2 (MFMA bf16) + fused attn2 epilogue; z2 stored bf16 ----------
__global__ __launch_bounds__(256) void gemm2_mfma_k(
        const unsigned short* __restrict__ h1, const short8* __restrict__ Wfrag,
        const float* __restrict__ av, const float* __restrict__ bv,
        unsigned short* __restrict__ z2b, float* __restrict__ as_, float* __restrict__ ad_) {
    int w = threadIdx.x >> 6, lane = threadIdx.x & 63;
    int quad = lane >> 4, l16 = lane & 15;
    int mA = blockIdx.x * 64 + w * 16 + l16;
    int mAl = min(mA, NNODES - 1);

    f32x4 acc[2];
    acc[0] = (f32x4){0.f, 0.f, 0.f, 0.f};
    acc[1] = (f32x4){0.f, 0.f, 0.f, 0.f};
    for (int kc = 0; kc < 8; ++kc) {
        int k0 = kc * 32 + quad * 8;
        short8 af = *(const short8*)(h1 + (size_t)mAl * 256 + k0);
#pragma unroll
        for (int nt = 0; nt < 2; ++nt) {
            short8 bf8 = Wfrag[kc * 128 + nt * 64 + lane];
            acc[nt] = __builtin_amdgcn_mfma_f32_16x16x32_bf16(af, bf8, acc[nt], 0, 0, 0);
        }
    }
    int mrow0 = blockIdx.x * 64 + w * 16 + quad * 4;
    float av0 = av[l16], av1v = av[16 + l16];
    float bv0 = bv[l16], bv1v = bv[16 + l16];
#pragma unroll
    for (int r = 0; r < 4; ++r) {
        int mr = mrow0 + r;
        float pa = acc[0][r] * av0 + acc[1][r] * av1v;
        float pb = acc[0][r] * bv0 + acc[1][r] * bv1v;
#pragma unroll
        for (int off = 1; off < 16; off <<= 1) {
            pa += __shfl_xor(pa, off, 64);
            pb += __shfl_xor(pb, off, 64);
        }
        if (mr < NNODES) {
            z2b[(size_t)mr * 32 + l16] = f2bf(acc[0][r]);
            z2b[(size_t)mr * 32 + 16 + l16] = f2bf(acc[1][r]);
            if (l16 == 0) { as_[mr] = pa; ad_[mr] = pb; }
        }
    }
}

// ---------- fused layer-1 aggregation: one wave per dst, 8-deep, shuffle-deduped ----------
__global__ void agg1_csr_k(const int* __restrict__ row_start, const int* __restrict__ csr_src,
                           const unsigned short* __restrict__ z, const float* __restrict__ as_,
                           const float* __restrict__ ad_, const float* __restrict__ b,
                           unsigned short* __restrict__ h1) {
    int wv = threadIdx.x >> 6, lane = threadIdx.x & 63;
    int d = blockIdx.x * 4 + wv;
    int h = lane >> 3;
    int c0 = lane * 4;
    int e8 = lane & 7;
    float adh = ad_[d * 8 + h];
    int beg = row_start[d], end = row_start[d + 1];
    float sum = 0.f, a0 = 0.f, a1 = 0.f, a2 = 0.f, a3 = 0.f;
    int i = beg;
    for (; i + 8 <= end; i += 8) {
        int sv = csr_src[i + e8];
        float myw = __expf(lrelu(as_[sv * 8 + h] + adh));
        int se[8];
        float we[8];
#pragma unroll
        for (int e = 0; e < 8; ++e) {
            se[e] = __shfl(sv, e, 64);
            we[e] = __shfl(myw, (lane & 56) | e, 64);
        }
        uint2 q[8];
#pragma unroll
        for (int e = 0; e < 8; ++e)
            q[e] = *(const uint2*)(z + (size_t)se[e] * 256 + c0);
#pragma unroll
        for (int e = 0; e < 8; ++e) {
            float wgt = we[e];
            sum += wgt;
            a0 += wgt * bflo(q[e].x);
            a1 += wgt * bfhi(q[e].x);
            a2 += wgt * bflo(q[e].y);
            a3 += wgt * bfhi(q[e].y);
        }
    }
    for (; i < end; ++i) {
        int s = csr_src[i];
        float wgt = __expf(lrelu(as_[s * 8 + h] + adh));
        uint2 zz = *(const uint2*)(z + (size_t)s * 256 + c0);
        sum += wgt;
        a0 += wgt * bflo(zz.x);
        a1 += wgt * bfhi(zz.x);
        a2 += wgt * bflo(zz.y);
        a3 += wgt * bfhi(zz.y);
    }
    float inv = 1.f / sum;
    float o0 = a0 * inv + b[c0 + 0];
    float o1 = a1 * inv + b[c0 + 1];
    float o2 = a2 * inv + b[c0 + 2];
    float o3 = a3 * inv + b[c0 + 3];
    o0 = o0 > 0.f ? o0 : expm1f(o0);
    o1 = o1 > 0.f ? o1 : expm1f(o1);
    o2 = o2 > 0.f ? o2 : expm1f(o2);
    o3 = o3 > 0.f ? o3 : expm1f(o3);
    uint2 pk;
    pk.x = (unsigned)f2bf(o0) | ((unsigned)f2bf(o1) << 16);
    pk.y = (unsigned)f2bf(o2) | ((unsigned)f2bf(o3) << 16);
    *(uint2*)(h1 + (size_t)d * 256 + c0) = pk;
}

// ---------- fused layer-2 aggregation + bias: 16 lanes/dst, 2 bf16 ch/lane ----------
__global__ void agg2_csr_k(const int* __restrict__ row_start, const int* __restrict__ csr_src,
                           const unsigned short* __restrict__ z2b, const float* __restrict__ as_,
                           const float* __restrict__ ad_, const float* __restrict__ b,
                           float* __restrict__ out) {
    int g = blockIdx.x * 16 + (threadIdx.x >> 4);   // 16 dsts per 256-thr block
    int l = threadIdx.x & 15;
    int lane = threadIdx.x & 63;
    int c0 = l * 2;
    int beg = row_start[g], end = row_start[g + 1];
    float adn = ad_[g];
    int e8 = l & 7;
    int gb = lane & 48;                             // 16-lane group base within wave
    float sum = 0.f, a0 = 0.f, a1 = 0.f;
    int i = beg;
    for (; i + 8 <= end; i += 8) {
        int sv = csr_src[i + e8];
        float myw = __expf(lrelu(as_[sv] + adn));
        int se[8];
        float we[8];
#pragma unroll
        for (int e = 0; e < 8; ++e) {
            se[e] = __shfl(sv, gb | e, 64);
            we[e] = __shfl(myw, gb | (8 | e), 64);  // lanes gb+8..gb+15 also computed e8=e weights
        }
        unsigned q[8];
#pragma unroll
        for (int e = 0; e < 8; ++e)
            q[e] = *(const unsigned*)(z2b + (size_t)se[e] * 32 + c0);
#pragma unroll
        for (int e = 0; e < 8; ++e) {
            float wgt = we[e];
            sum += wgt;
            a0 += wgt * bflo(q[e]);
            a1 += wgt * bfhi(q[e]);
        }
    }
    for (; i < end; ++i) {
        int s = csr_src[i];
        float wgt = __expf(lrelu(as_[s] + adn));
        unsigned q = *(const unsigned*)(z2b + (size_t)s * 32 + c0);
        sum += wgt;
        a0 += wgt * bflo(q);
        a1 += wgt * bfhi(q);
    }
    float inv = 1.f / sum;
    float2 o;
    o.x = a0 * inv + b[c0];
    o.y = a1 * inv + b[c0 + 1];
    *(float2*)(out + (size_t)g * 32 + c0) = o;
}

extern "C" void kernel_launch(void* const* d_in, const int* in_sizes, int n_in,
                              void* d_out, int out_size, void* d_ws, size_t ws_size,
                              hipStream_t stream) {
    const float* x   = (const float*)d_in[0];
    const int*   ei  = (const int*)d_in[1];
    const float* W1  = (const float*)d_in[2];
    const float* av1 = (const float*)d_in[3];
    const float* bv1 = (const float*)d_in[4];
    const float* b1  = (const float*)d_in[5];
    const float* W2  = (const float*)d_in[6];
    const float* av2 = (const float*)d_in[7];
    const float* bv2 = (const float*)d_in[8];
    const float* b2  = (const float*)d_in[9];
    float* out = (float*)d_out;

    // workspace layout (4-byte units)
    unsigned short* z1 = (unsigned short*)d_ws;            // 12.8M bf16 = 6.4M u32
    unsigned short* h1 = (unsigned short*)((float*)d_ws + 6400000);  // 12.8M bf16
    float* as1 = (float*)d_ws + 12800000;                  // 400,000
    float* ad1 = as1 + 400000;                             // 400,000
    unsigned short* z2b = (unsigned short*)(ad1 + 400000); // 1.6M bf16 = 800,000 u32
    float* as2 = ad1 + 400000 + 800000;                    // 50,000
    float* ad2 = as2 + 50000;                              // 50,000
    short8* W1frag = (short8*)(ad2 + 50000);               // 8192 * 16 B
    short8* W2frag = W1frag + 8192;                        // 1024 * 16 B
    int* deg       = (int*)(ad2 + 50000) + 36864;          // 50,000
    int* cursor    = deg + 50000;                          // 50,000
    int* row_start = cursor + 50000;                       // 50,001
    int* csr_src   = row_start + 50001;                    // 850,000
    int* row_local = csr_src + 850000;                     // 50,000
    int* bsum      = row_local + 50000;                    // 256

    hipMemsetAsync(deg, 0, (size_t)100000 * 4, stream);    // deg + cursor

    // ---- weight prep + CSR build ----
    wprep_hist_k<<<36 + SCAT_BLKS, 256, 0, stream>>>(W1, W2, W1frag, W2frag, ei, deg);
    scan_part_k<<<NSCAN_BLK, 256, 0, stream>>>(deg, row_local, bsum);
    scan_fix_k<<<NSCAN_BLK, 256, 0, stream>>>(row_local, bsum, row_start);

    // ---- layer 1 (gemm1 fused with CSR scatter) ----
    gemm1_scatter_k<<<GEMM1_BLKS + SCAT_BLKS, 256, 0, stream>>>(
        x, W1frag, av1, bv1, z1, as1, ad1, ei, row_start, cursor, csr_src);
    agg1_csr_k<<<(NNODES + 3) / 4, 256, 0, stream>>>(row_start, csr_src, z1, as1, ad1, b1, h1);

    // ---- layer 2 ----
    gemm2_mfma_k<<<(NNODES + 63) / 64, 256, 0, stream>>>(h1, W2frag, av2, bv2, z2b, as2, ad2);
    agg2_csr_k<<<NNODES / 16, 256, 0, stream>>>(row_start, csr_src, z2b, as2, ad2, b2, out);
}